// Round 10
// baseline (145.593 us; speedup 1.0000x reference)
//
#include <hip/hip_runtime.h>

using u16 = unsigned short;
using u32 = unsigned int;
typedef __attribute__((ext_vector_type(8))) short bf16x8;
typedef __attribute__((ext_vector_type(4))) float f32x4;

__device__ __forceinline__ float bf2f(u16 h) {
  union { u32 u; float f; } c; c.u = (u32)h << 16; return c.f;
}
__device__ __forceinline__ u16 f2bf(float f) {
  union { float f; u32 u; } c; c.f = f;
  u32 u = c.u;
  u32 r = (u + 0x7FFFu + ((u >> 16) & 1u)) >> 16;
  return (u16)r;
}

#define GLD16(gsrc, ldst)                                                      \
  __builtin_amdgcn_global_load_lds(                                            \
      (const __attribute__((address_space(1))) unsigned int*)(gsrc),           \
      (__attribute__((address_space(3))) unsigned int*)(ldst), 16, 0, 0)

// kappa: virtual key order inside a 64-key tile so PV's A-frag is the natural
// register layout of the swapped QK^T output.
__device__ __forceinline__ int kappa(int ss) {
  return (ss & 0x23) | ((ss & 0x10) >> 2) | ((ss & 0x0C) << 1);
}

// ---------------------------------------------------------------- convert
__global__ void cvt_kernel(const float* __restrict__ src, u16* __restrict__ dst, int n) {
  int i = (blockIdx.x * blockDim.x + threadIdx.x) * 4;
  if (i < n) {
    float4 v = *(const float4*)(src + i);
    ushort4 o;
    o.x = f2bf(v.x); o.y = f2bf(v.y); o.z = f2bf(v.z); o.w = f2bf(v.w);
    *(ushort4*)(dst + i) = o;
  }
}

// ---------------------------------------------------------------- rel-pos table
__global__ void tbl_kernel(const float* __restrict__ rph, const float* __restrict__ rpw,
                           u16* __restrict__ tbl) {
  int i = blockIdx.x * 256 + threadIdx.x;  // 8192 total
  int row = i >> 6, d = i & 63;
  float v = 0.f;
  if (row < 63) v = rph[row * 64 + d];
  else if (row >= 64 && row < 127) v = rpw[(row - 64) * 64 + d];
  tbl[i] = f2bf(v * 1.44269504f);
}

// ---------------------------------------------------------------- P gemm
// P[g][j] = q[g][:] . tbl[j][:]   (98304 x 128 x 64), bf16 out (log2 domain)
__global__ __launch_bounds__(256, 2) void pgemm_kernel(
    const u16* __restrict__ A, const u16* __restrict__ tbl, u16* __restrict__ P) {
  __shared__ u16 As[128 * 64];
  __shared__ u16 Bs[128 * 64];
  const int tid = threadIdx.x;
  const int lane = tid & 63, wave = tid >> 6;
  const int lr = lane & 15, lg = lane >> 4;
  const int m0 = blockIdx.x * 128;
  const int wm = (wave >> 1) * 64, wn = (wave & 1) * 64;

#pragma unroll
  for (int i = 0; i < 4; ++i) {
    int c = tid + i * 256;
    int row = c >> 3, pp = c & 7;
    int pl = pp ^ (row & 7);  // pre-swizzled source, linear LDS dest
    GLD16(A + (size_t)(m0 + row) * 64 + pl * 8, &As[c * 8]);
    GLD16(tbl + row * 64 + pl * 8, &Bs[c * 8]);
  }
  __syncthreads();

  bf16x8 a[4][2], b[4][2];
#pragma unroll
  for (int m = 0; m < 4; ++m) {
    int row = wm + m * 16 + lr;
#pragma unroll
    for (int kf = 0; kf < 2; ++kf)
      a[m][kf] = *(const bf16x8*)&As[(row * 64 + kf * 32 + lg * 8) ^ ((row & 7) << 3)];
  }
#pragma unroll
  for (int n = 0; n < 4; ++n) {
    int row = wn + n * 16 + lr;
#pragma unroll
    for (int kf = 0; kf < 2; ++kf)
      b[n][kf] = *(const bf16x8*)&Bs[(row * 64 + kf * 32 + lg * 8) ^ ((row & 7) << 3)];
  }

  f32x4 acc[4][4] = {};
#pragma unroll
  for (int kf = 0; kf < 2; ++kf)
#pragma unroll
    for (int m = 0; m < 4; ++m)
#pragma unroll
      for (int n = 0; n < 4; ++n)
        acc[m][n] = __builtin_amdgcn_mfma_f32_16x16x32_bf16(a[m][kf], b[n][kf], acc[m][n], 0, 0, 0);

#pragma unroll
  for (int m = 0; m < 4; ++m)
#pragma unroll
    for (int n = 0; n < 4; ++n) {
      const int col = wn + n * 16 + lr;
#pragma unroll
      for (int r = 0; r < 4; ++r) {
        const int g = m0 + wm + m * 16 + lg * 4 + r;
        P[(size_t)g * 128 + col] = f2bf(acc[m][n][r]);
      }
    }
}

// ---------------------------------------------------------------- GEMM
// 128x128 tile, BK=64, 512 threads / 8 waves (wave tile 64x32), XOR-swizzled
// LDS, XCD block swizzle, counted vmcnt, loop-carried staging pointers.
template <int MODE>
__global__ __launch_bounds__(512, 2) void gemm128(
    const u16* __restrict__ A, const u16* __restrict__ B,
    const float* __restrict__ bias, u16* __restrict__ oq, u16* __restrict__ ok,
    u16* __restrict__ ovt, float* __restrict__ ofp) {
  __shared__ u16 As[2][128 * 64];
  __shared__ u16 Bs[2][128 * 64];
  const int tid = threadIdx.x;
  const int lane = tid & 63, wave = tid >> 6;
  const int lr = lane & 15, lg = lane >> 4;

  const int nbx = (MODE == 0) ? 18 : 6;
  const int nwg = nbx * 64;
  int id = blockIdx.y * nbx + blockIdx.x;
  int nid = (id & 7) * (nwg >> 3) + (id >> 3);
  const int m0 = (nid / nbx) * 128, n0 = (nid % nbx) * 128;
  const int wm = (wave >> 2) * 64, wn = (wave & 3) * 32;

  f32x4 acc[4][2] = {};

  // loop-carried staging pointers: computed once, advanced by constants
  const u16* ap[2];
  const u16* bp[2];
#pragma unroll
  for (int i = 0; i < 2; ++i) {
    int c = tid + i * 512;          // 1024 chunks = 128 rows x 8
    int row = c >> 3, pp = c & 7;
    int pl = pp ^ (row & 7);        // pre-swizzled global source, linear LDS dest
    if constexpr (MODE == 0) {
      ap[i] = A + (size_t)(m0 + row) * 768 + pl * 8;
    } else {
      int g = m0 + row;
      ap[i] = A + ((size_t)((g >> 10) * 12) << 16) + (g & 1023) * 64 + pl * 8;
    }
    bp[i] = B + (size_t)(n0 + row) * 768 + pl * 8;
  }
  constexpr int dA = (MODE == 0) ? 64 : 65536;

  auto stage = [&](int bi) {
#pragma unroll
    for (int i = 0; i < 2; ++i) {
      int c = tid + i * 512;
      GLD16(ap[i], &As[bi][c * 8]);
      GLD16(bp[i], &Bs[bi][c * 8]);
      ap[i] += dA;
      bp[i] += 64;
    }
  };

  stage(0);
#pragma unroll 1
  for (int t = 0; t < 12; ++t) {
    const int cur = t & 1;
    if (t < 11) {
      stage(cur ^ 1);
      asm volatile("s_waitcnt vmcnt(4)" ::: "memory");
    } else {
      asm volatile("s_waitcnt vmcnt(0)" ::: "memory");
    }
    __builtin_amdgcn_sched_barrier(0);
    __builtin_amdgcn_s_barrier();        // entry: buf[cur] ready for all waves
    __builtin_amdgcn_sched_barrier(0);

    bf16x8 a[4][2], b[2][2];
#pragma unroll
    for (int m = 0; m < 4; ++m) {
      int row = wm + m * 16 + lr;
#pragma unroll
      for (int kf = 0; kf < 2; ++kf)
        a[m][kf] = *(const bf16x8*)&As[cur][(row * 64 + kf * 32 + lg * 8) ^ ((row & 7) << 3)];
    }
#pragma unroll
    for (int n = 0; n < 2; ++n) {
      int row = wn + n * 16 + lr;
#pragma unroll
      for (int kf = 0; kf < 2; ++kf)
        b[n][kf] = *(const bf16x8*)&Bs[cur][(row * 64 + kf * 32 + lg * 8) ^ ((row & 7) << 3)];
    }
    __builtin_amdgcn_s_setprio(1);
#pragma unroll
    for (int kf = 0; kf < 2; ++kf)
#pragma unroll
      for (int m = 0; m < 4; ++m)
#pragma unroll
        for (int n = 0; n < 2; ++n)
          acc[m][n] = __builtin_amdgcn_mfma_f32_16x16x32_bf16(a[m][kf], b[n][kf], acc[m][n], 0, 0, 0);
    __builtin_amdgcn_s_setprio(0);

    __builtin_amdgcn_sched_barrier(0);
    __builtin_amdgcn_s_barrier();        // exit: all reads done before overwrite
    __builtin_amdgcn_sched_barrier(0);
  }

#pragma unroll
  for (int m = 0; m < 4; ++m) {
    const int grow0 = m0 + wm + m * 16 + lg * 4;
#pragma unroll
    for (int n = 0; n < 2; ++n) {
      const int gcol = n0 + wn + n * 16 + lr;
      const float bv = bias[gcol];
      if constexpr (MODE == 0) {
        int which = (gcol >= 1536) ? 2 : (gcol >= 768 ? 1 : 0);
        int rem = gcol - which * 768;
        int bh = (grow0 >> 10) * 12 + (rem >> 6);
        if (which == 2) {
          int s0 = grow0 & 1023;
          int colb = (s0 & ~63) | kappa(s0 & 63);  // kappa keeps low 2 bits
          ushort4 pk;
          pk.x = f2bf(acc[m][n][0] + bv);
          pk.y = f2bf(acc[m][n][1] + bv);
          pk.z = f2bf(acc[m][n][2] + bv);
          pk.w = f2bf(acc[m][n][3] + bv);
          *(ushort4*)&ovt[((size_t)bh << 16) + (size_t)(rem & 63) * 1024 + colb] = pk;
        } else {
          u16* dst = (which == 0) ? oq : ok;
#pragma unroll
          for (int r = 0; r < 4; ++r) {
            int s = (grow0 & 1023) + r;
            dst[((size_t)bh << 16) + s * 64 + (rem & 63)] = f2bf(acc[m][n][r] + bv);
          }
        }
      } else {
#pragma unroll
        for (int r = 0; r < 4; ++r)
          ofp[(size_t)(grow0 + r) * 768 + gcol] = acc[m][n][r] + bv;
      }
    }
  }
}

// ---------------------------------------------------------------- flash attention
// grid (96 heads, 8 q-tiles); block 256 = 4 waves x 32 q-rows.
// Proven 2-deep / 2-barrier structure (round 7) + launch_bounds(256,4):
// 32 KB LDS and VGPR<=128 allow 3+ resident blocks/CU so one block's
// barrier/vmcnt stalls hide under another's MFMA.
__global__ __launch_bounds__(256, 4) void attn_kernel(
    const u16* __restrict__ qb, const u16* __restrict__ kb,
    const u16* __restrict__ vtb, const u16* __restrict__ pb,
    u16* __restrict__ ao) {
  __shared__ u16 Ks[2][64 * 64];
  __shared__ u16 Vs[2][64 * 64];

  const int tid = threadIdx.x;
  const int lane = tid & 63, wave = tid >> 6;
  const int lr = lane & 15, lg = lane >> 4;
  const int bh = blockIdx.x;   // head fastest -> all q-tiles of a head on one XCD
  const int q0 = blockIdx.y * 128 + wave * 32;
  const size_t hb = (size_t)bh << 16;

  bf16x8 qf[2][2];
#pragma unroll
  for (int m = 0; m < 2; ++m)
#pragma unroll
    for (int kf = 0; kf < 2; ++kf)
      qf[m][kf] = *(const bf16x8*)(qb + hb + (size_t)(q0 + m * 16 + lr) * 64 + kf * 32 + lg * 8);

  // rel_w bias (log2 domain), per lane's own q-row g = q0+m*16+lr
  float rwv[2][2][4];
  const u16* bp[2];  // rel_h bias pointer per m, walks down 2 u16 per tile
#pragma unroll
  for (int m = 0; m < 2; ++m) {
    int g = q0 + m * 16 + lr;
    const size_t pbase = (((size_t)bh << 10) + g) * 128;
    int w = g & 31;
#pragma unroll
    for (int i = 0; i < 2; ++i)
#pragma unroll
      for (int r = 0; r < 4; ++r) {
        int kw = i * 16 + lg * 4 + r;
        rwv[m][i][r] = bf2f(pb[pbase + 95 + w - kw]);
      }
    bp[m] = pb + pbase + (g >> 5) + 31;  // kh0=0 position
  }

  // current-tile rel_h bias values (u16), pipelined one tile ahead
  u16 bc0[2], bc1[2];
#pragma unroll
  for (int m = 0; m < 2; ++m) { bc0[m] = bp[m][0]; bc1[m] = bp[m][-1]; }

  float lsum[2] = {};
  f32x4 acco[2][4] = {};

  // loop-carried staging pointers
  const u16* kp[2];
  const u16* vp[2];
#pragma unroll
  for (int i = 0; i < 2; ++i) {
    int c = tid + i * 256;
    int row = c >> 3, pp = c & 7;
    int pl = pp ^ (row & 7);  // pre-swizzled global source, linear LDS dest
    kp[i] = kb + hb + (size_t)row * 64 + pl * 8;       // += 4096 per tile
    vp[i] = vtb + hb + (size_t)row * 1024 + pl * 8;    // += 64 per tile
  }

  auto stage = [&](int bi) {
#pragma unroll
    for (int i = 0; i < 2; ++i) {
      int c = tid + i * 256;
      GLD16(kp[i], &Ks[bi][c * 8]);
      GLD16(vp[i], &Vs[bi][c * 8]);
      kp[i] += 4096;
      vp[i] += 64;
    }
  };

  stage(0);

  const float scale2 = 0.125f * 1.44269504f;

#pragma unroll 1
  for (int t = 0; t < 16; ++t) {
    const int cur = t & 1;
    u16 bn0[2], bn1[2];
    if (t < 15) {
      stage(cur ^ 1);
      // issue next tile's rel_h bias loads now; consumed next iteration
#pragma unroll
      for (int m = 0; m < 2; ++m) { bn0[m] = bp[m][-2]; bn1[m] = bp[m][-3]; }
      asm volatile("s_waitcnt vmcnt(8)" ::: "memory");
    } else {
      asm volatile("s_waitcnt vmcnt(0)" ::: "memory");
    }
    __builtin_amdgcn_sched_barrier(0);
    __builtin_amdgcn_s_barrier();        // entry: buf[cur] ready
    __builtin_amdgcn_sched_barrier(0);

    // QK^T (swapped): sac[m][f] col=lr -> q, row=lg*4+r -> k=f*16+lg*4+r
    f32x4 sac[2][4] = {};
    __builtin_amdgcn_s_setprio(1);
#pragma unroll
    for (int kf = 0; kf < 2; ++kf) {
#pragma unroll
      for (int f = 0; f < 4; ++f) {
        int row = f * 16 + lr;
        bf16x8 kv = *(const bf16x8*)&Ks[cur][(row * 64 + kf * 32 + lg * 8) ^ ((row & 7) << 3)];
#pragma unroll
        for (int m = 0; m < 2; ++m)
          sac[m][f] = __builtin_amdgcn_mfma_f32_16x16x32_bf16(kv, qf[m][kf], sac[m][f], 0, 0, 0);
      }
    }
    __builtin_amdgcn_s_setprio(0);

    // bias + exp2 + in-register P (A-frag via kappa order, zero cross-lane)
    bf16x8 paf[2][2];
#pragma unroll
    for (int m = 0; m < 2; ++m) {
      float c0 = bf2f(bc0[m]), c1 = bf2f(bc1[m]);
      float bs[2][2][4];  // [j = b0/b1][i][r]
#pragma unroll
      for (int i = 0; i < 2; ++i)
#pragma unroll
        for (int r = 0; r < 4; ++r) {
          bs[0][i][r] = c0 + rwv[m][i][r];
          bs[1][i][r] = c1 + rwv[m][i][r];
        }
      union { u32 w[4]; bf16x8 v; } wa, wb;
#pragma unroll
      for (int f = 0; f < 4; ++f) {
        const int j = (f >> 1) & 1, i = f & 1;
        float p0 = __builtin_amdgcn_exp2f(sac[m][f][0] * scale2 + bs[j][i][0]);
        float p1 = __builtin_amdgcn_exp2f(sac[m][f][1] * scale2 + bs[j][i][1]);
        float p2 = __builtin_amdgcn_exp2f(sac[m][f][2] * scale2 + bs[j][i][2]);
        float p3 = __builtin_amdgcn_exp2f(sac[m][f][3] * scale2 + bs[j][i][3]);
        lsum[m] += (p0 + p1) + (p2 + p3);
        u32 w0, w1;
        asm("v_cvt_pk_bf16_f32 %0, %1, %2" : "=v"(w0) : "v"(p0), "v"(p1));
        asm("v_cvt_pk_bf16_f32 %0, %1, %2" : "=v"(w1) : "v"(p2), "v"(p3));
        if (f < 2) { wa.w[f * 2] = w0; wa.w[f * 2 + 1] = w1; }
        else       { wb.w[(f - 2) * 2] = w0; wb.w[(f - 2) * 2 + 1] = w1; }
      }
      paf[m][0] = wa.v;
      paf[m][1] = wb.v;
    }

    // PV: O[q][d], acco row=lg*4+r -> q, col=lr -> d
    __builtin_amdgcn_s_setprio(1);
#pragma unroll
    for (int kf = 0; kf < 2; ++kf) {
#pragma unroll
      for (int fd = 0; fd < 4; ++fd) {
        int drow = fd * 16 + lr;
        bf16x8 vv = *(const bf16x8*)&Vs[cur][(drow * 64 + kf * 32 + lg * 8) ^ ((drow & 7) << 3)];
#pragma unroll
        for (int m = 0; m < 2; ++m)
          acco[m][fd] = __builtin_amdgcn_mfma_f32_16x16x32_bf16(paf[m][kf], vv, acco[m][fd], 0, 0, 0);
      }
    }
    __builtin_amdgcn_s_setprio(0);

    if (t < 15) {
#pragma unroll
      for (int m = 0; m < 2; ++m) {
        bc0[m] = bn0[m];
        bc1[m] = bn1[m];
        bp[m] -= 2;
      }
    }

    __builtin_amdgcn_sched_barrier(0);
    __builtin_amdgcn_s_barrier();        // exit: reads done before overwrite
    __builtin_amdgcn_sched_barrier(0);
  }

#pragma unroll
  for (int m = 0; m < 2; ++m) {
    float s = lsum[m];
    s += __shfl_xor(s, 16);
    s += __shfl_xor(s, 32);
    float inv = 1.0f / s;  // valid on lane with lr = q-local, any lg
#pragma unroll
    for (int r = 0; r < 4; ++r) {
      int src = (lane & 48) + ((lane & 48) >> 2) + r;
      float invr = __shfl(inv, src);
      int gq = q0 + m * 16 + lg * 4 + r;
#pragma unroll
      for (int fd = 0; fd < 4; ++fd)
        ao[hb + (size_t)gq * 64 + fd * 16 + lr] = f2bf(acco[m][fd][r] * invr);
    }
  }
}

// ---------------------------------------------------------------- launch
extern "C" void kernel_launch(void* const* d_in, const int* in_sizes, int n_in,
                              void* d_out, int out_size, void* d_ws, size_t ws_size,
                              hipStream_t stream) {
  const float* x = (const float*)d_in[0];
  const float* qkv_w = (const float*)d_in[1];
  const float* qkv_b = (const float*)d_in[2];
  const float* proj_w = (const float*)d_in[3];
  const float* proj_b = (const float*)d_in[4];
  const float* rel_pos_h = (const float*)d_in[5];
  const float* rel_pos_w = (const float*)d_in[6];
  float* out = (float*)d_out;

  char* ws = (char*)d_ws;
  u16* x_bf = (u16*)(ws + 0);              // 12,582,912 B (reused as attn out)
  u16* qkvw_bf = (u16*)(ws + 12582912);    //  3,538,944
  u16* projw_bf = (u16*)(ws + 16121856);   //  1,179,648
  u16* qbuf = (u16*)(ws + 17301504);       // 12,582,912
  u16* kbuf = (u16*)(ws + 29884416);       // 12,582,912
  u16* vtbuf = (u16*)(ws + 42467328);      // 12,582,912
  u16* pbuf = (u16*)(ws + 55050240);       // 25,165,824 (98304 x 128 bf16)
  u16* tbl = (u16*)(ws + 80216064);        //     16,384 -> total 80,232,448
  u16* aobuf = x_bf;                        // alias: x_bf dead after QKV gemm

  cvt_kernel<<<6144, 256, 0, stream>>>(x, x_bf, 6291456);
  cvt_kernel<<<1728, 256, 0, stream>>>(qkv_w, qkvw_bf, 1769472);
  cvt_kernel<<<576, 256, 0, stream>>>(proj_w, projw_bf, 589824);
  tbl_kernel<<<32, 256, 0, stream>>>(rel_pos_h, rel_pos_w, tbl);

  gemm128<0><<<dim3(18, 64), 512, 0, stream>>>(x_bf, qkvw_bf, qkv_b, qbuf, kbuf, vtbuf, nullptr);

  pgemm_kernel<<<768, 256, 0, stream>>>(qbuf, tbl, pbuf);

  attn_kernel<<<dim3(96, 8), 256, 0, stream>>>(qbuf, kbuf, vtbuf, pbuf, aobuf);

  gemm128<1><<<dim3(6, 64), 512, 0, stream>>>(aobuf, projw_bf, proj_b, nullptr, nullptr, nullptr, out);
}

// Round 11
// 135.146 us; speedup vs baseline: 1.0773x; 1.0773x over previous
//
#include <hip/hip_runtime.h>

using u16 = unsigned short;
using u32 = unsigned int;
typedef __attribute__((ext_vector_type(8))) short bf16x8;
typedef __attribute__((ext_vector_type(4))) float f32x4;

__device__ __forceinline__ float bf2f(u32 h) {
  union { u32 u; float f; } c; c.u = h << 16; return c.f;
}
__device__ __forceinline__ u16 f2bf(float f) {
  union { float f; u32 u; } c; c.f = f;
  u32 u = c.u;
  u32 r = (u + 0x7FFFu + ((u >> 16) & 1u)) >> 16;
  return (u16)r;
}

#define GLD16(gsrc, ldst)                                                      \
  __builtin_amdgcn_global_load_lds(                                            \
      (const __attribute__((address_space(1))) unsigned int*)(gsrc),           \
      (__attribute__((address_space(3))) unsigned int*)(ldst), 16, 0, 0)

// kappa: virtual key order inside a 64-key tile so PV's A-frag is the natural
// register layout of the swapped QK^T output.
__device__ __forceinline__ int kappa(int ss) {
  return (ss & 0x23) | ((ss & 0x10) >> 2) | ((ss & 0x0C) << 1);
}

// ---------------------------------------------------------------- convert
__global__ void cvt_kernel(const float* __restrict__ src, u16* __restrict__ dst, int n) {
  int i = (blockIdx.x * blockDim.x + threadIdx.x) * 4;
  if (i < n) {
    float4 v = *(const float4*)(src + i);
    ushort4 o;
    o.x = f2bf(v.x); o.y = f2bf(v.y); o.z = f2bf(v.z); o.w = f2bf(v.w);
    *(ushort4*)(dst + i) = o;
  }
}

// ---------------------------------------------------------------- rel-pos table
__global__ void tbl_kernel(const float* __restrict__ rph, const float* __restrict__ rpw,
                           u16* __restrict__ tbl) {
  int i = blockIdx.x * 256 + threadIdx.x;  // 8192 total
  int row = i >> 6, d = i & 63;
  float v = 0.f;
  if (row < 63) v = rph[row * 64 + d];
  else if (row >= 64 && row < 127) v = rpw[(row - 64) * 64 + d];
  tbl[i] = f2bf(v * 1.44269504f);
}

// ---------------------------------------------------------------- P gemm
// Computes q[g].tbl[j] then scatters into per-row strips P2[g][64]:
//   [0..31]  = rel_w(g, kw)  (kw = w+95-col, col>=64)
//   [32..63] = rel_h(g, kh)  (kh = hq+31-col, col<64)
// so the attention kernel can load all bias for a row with aligned vector
// loads BEFORE its K-loop (no in-loop VMEM->VGPR => counted vmcnt works).
__global__ __launch_bounds__(256, 2) void pgemm_kernel(
    const u16* __restrict__ A, const u16* __restrict__ tbl, u16* __restrict__ P) {
  __shared__ u16 As[128 * 64];
  __shared__ u16 Bs[128 * 64];
  const int tid = threadIdx.x;
  const int lane = tid & 63, wave = tid >> 6;
  const int lr = lane & 15, lg = lane >> 4;
  const int m0 = blockIdx.x * 128;
  const int wm = (wave >> 1) * 64, wn = (wave & 1) * 64;

#pragma unroll
  for (int i = 0; i < 4; ++i) {
    int c = tid + i * 256;
    int row = c >> 3, pp = c & 7;
    int pl = pp ^ (row & 7);  // pre-swizzled source, linear LDS dest
    GLD16(A + (size_t)(m0 + row) * 64 + pl * 8, &As[c * 8]);
    GLD16(tbl + row * 64 + pl * 8, &Bs[c * 8]);
  }
  __syncthreads();

  bf16x8 a[4][2], b[4][2];
#pragma unroll
  for (int m = 0; m < 4; ++m) {
    int row = wm + m * 16 + lr;
#pragma unroll
    for (int kf = 0; kf < 2; ++kf)
      a[m][kf] = *(const bf16x8*)&As[(row * 64 + kf * 32 + lg * 8) ^ ((row & 7) << 3)];
  }
#pragma unroll
  for (int n = 0; n < 4; ++n) {
    int row = wn + n * 16 + lr;
#pragma unroll
    for (int kf = 0; kf < 2; ++kf)
      b[n][kf] = *(const bf16x8*)&Bs[(row * 64 + kf * 32 + lg * 8) ^ ((row & 7) << 3)];
  }

  f32x4 acc[4][4] = {};
#pragma unroll
  for (int kf = 0; kf < 2; ++kf)
#pragma unroll
    for (int m = 0; m < 4; ++m)
#pragma unroll
      for (int n = 0; n < 4; ++n)
        acc[m][n] = __builtin_amdgcn_mfma_f32_16x16x32_bf16(a[m][kf], b[n][kf], acc[m][n], 0, 0, 0);

#pragma unroll
  for (int m = 0; m < 4; ++m)
#pragma unroll
    for (int n = 0; n < 4; ++n) {
      const int col = wn + n * 16 + lr;
#pragma unroll
      for (int r = 0; r < 4; ++r) {
        const int g = m0 + wm + m * 16 + lg * 4 + r;
        const int s = g & 1023;
        const int hq = s >> 5, w = s & 31;
        u16 hv = f2bf(acc[m][n][r]);
        if (col < 64) {
          int kh = hq + 31 - col;
          if ((unsigned)kh < 32u) P[(size_t)g * 64 + 32 + kh] = hv;
        } else {
          int kw = w + 95 - col;
          if ((unsigned)kw < 32u) P[(size_t)g * 64 + kw] = hv;
        }
      }
    }
}

// ---------------------------------------------------------------- GEMM
// 128x128 tile, BK=64, 512 threads / 8 waves (wave tile 64x32), XOR-swizzled
// LDS, XCD block swizzle, counted vmcnt, loop-carried staging pointers.
template <int MODE>
__global__ __launch_bounds__(512, 2) void gemm128(
    const u16* __restrict__ A, const u16* __restrict__ B,
    const float* __restrict__ bias, u16* __restrict__ oq, u16* __restrict__ ok,
    u16* __restrict__ ovt, float* __restrict__ ofp) {
  __shared__ u16 As[2][128 * 64];
  __shared__ u16 Bs[2][128 * 64];
  const int tid = threadIdx.x;
  const int lane = tid & 63, wave = tid >> 6;
  const int lr = lane & 15, lg = lane >> 4;

  const int nbx = (MODE == 0) ? 18 : 6;
  const int nwg = nbx * 64;
  int id = blockIdx.y * nbx + blockIdx.x;
  int nid = (id & 7) * (nwg >> 3) + (id >> 3);
  const int m0 = (nid / nbx) * 128, n0 = (nid % nbx) * 128;
  const int wm = (wave >> 2) * 64, wn = (wave & 3) * 32;

  f32x4 acc[4][2] = {};

  // loop-carried staging pointers: computed once, advanced by constants
  const u16* ap[2];
  const u16* bp[2];
#pragma unroll
  for (int i = 0; i < 2; ++i) {
    int c = tid + i * 512;          // 1024 chunks = 128 rows x 8
    int row = c >> 3, pp = c & 7;
    int pl = pp ^ (row & 7);        // pre-swizzled global source, linear LDS dest
    if constexpr (MODE == 0) {
      ap[i] = A + (size_t)(m0 + row) * 768 + pl * 8;
    } else {
      int g = m0 + row;
      ap[i] = A + ((size_t)((g >> 10) * 12) << 16) + (g & 1023) * 64 + pl * 8;
    }
    bp[i] = B + (size_t)(n0 + row) * 768 + pl * 8;
  }
  constexpr int dA = (MODE == 0) ? 64 : 65536;

  auto stage = [&](int bi) {
#pragma unroll
    for (int i = 0; i < 2; ++i) {
      int c = tid + i * 512;
      GLD16(ap[i], &As[bi][c * 8]);
      GLD16(bp[i], &Bs[bi][c * 8]);
      ap[i] += dA;
      bp[i] += 64;
    }
  };

  stage(0);
#pragma unroll 1
  for (int t = 0; t < 12; ++t) {
    const int cur = t & 1;
    if (t < 11) {
      stage(cur ^ 1);
      asm volatile("s_waitcnt vmcnt(4)" ::: "memory");
    } else {
      asm volatile("s_waitcnt vmcnt(0)" ::: "memory");
    }
    __builtin_amdgcn_sched_barrier(0);
    __builtin_amdgcn_s_barrier();        // entry: buf[cur] ready for all waves
    __builtin_amdgcn_sched_barrier(0);

    bf16x8 a[4][2], b[2][2];
#pragma unroll
    for (int m = 0; m < 4; ++m) {
      int row = wm + m * 16 + lr;
#pragma unroll
      for (int kf = 0; kf < 2; ++kf)
        a[m][kf] = *(const bf16x8*)&As[cur][(row * 64 + kf * 32 + lg * 8) ^ ((row & 7) << 3)];
    }
#pragma unroll
    for (int n = 0; n < 2; ++n) {
      int row = wn + n * 16 + lr;
#pragma unroll
      for (int kf = 0; kf < 2; ++kf)
        b[n][kf] = *(const bf16x8*)&Bs[cur][(row * 64 + kf * 32 + lg * 8) ^ ((row & 7) << 3)];
    }
    __builtin_amdgcn_s_setprio(1);
#pragma unroll
    for (int kf = 0; kf < 2; ++kf)
#pragma unroll
      for (int m = 0; m < 4; ++m)
#pragma unroll
        for (int n = 0; n < 2; ++n)
          acc[m][n] = __builtin_amdgcn_mfma_f32_16x16x32_bf16(a[m][kf], b[n][kf], acc[m][n], 0, 0, 0);
    __builtin_amdgcn_s_setprio(0);

    __builtin_amdgcn_sched_barrier(0);
    __builtin_amdgcn_s_barrier();        // exit: all reads done before overwrite
    __builtin_amdgcn_sched_barrier(0);
  }

#pragma unroll
  for (int m = 0; m < 4; ++m) {
    const int grow0 = m0 + wm + m * 16 + lg * 4;
#pragma unroll
    for (int n = 0; n < 2; ++n) {
      const int gcol = n0 + wn + n * 16 + lr;
      const float bv = bias[gcol];
      if constexpr (MODE == 0) {
        int which = (gcol >= 1536) ? 2 : (gcol >= 768 ? 1 : 0);
        int rem = gcol - which * 768;
        int bh = (grow0 >> 10) * 12 + (rem >> 6);
        if (which == 2) {
          int s0 = grow0 & 1023;
          int colb = (s0 & ~63) | kappa(s0 & 63);  // kappa keeps low 2 bits
          ushort4 pk;
          pk.x = f2bf(acc[m][n][0] + bv);
          pk.y = f2bf(acc[m][n][1] + bv);
          pk.z = f2bf(acc[m][n][2] + bv);
          pk.w = f2bf(acc[m][n][3] + bv);
          *(ushort4*)&ovt[((size_t)bh << 16) + (size_t)(rem & 63) * 1024 + colb] = pk;
        } else {
          u16* dst = (which == 0) ? oq : ok;
#pragma unroll
          for (int r = 0; r < 4; ++r) {
            int s = (grow0 & 1023) + r;
            dst[((size_t)bh << 16) + s * 64 + (rem & 63)] = f2bf(acc[m][n][r] + bv);
          }
        }
      } else {
#pragma unroll
        for (int r = 0; r < 4; ++r)
          ofp[(size_t)(grow0 + r) * 768 + gcol] = acc[m][n][r] + bv;
      }
    }
  }
}

// ---------------------------------------------------------------- flash attention
// grid (96 heads, 8 q-tiles); block 256 = 4 waves x 32 q-rows.
// 2-deep / 2-barrier (round-7 structure). ALL bias preloaded before the loop
// from the per-row strip table P2[g][64] (rel_w [0..31], rel_h [32..63]):
// the K-loop has ZERO VMEM->VGPR loads, so vmcnt(4) genuinely leaves the
// next tile's stage loads in flight (previously the per-tile bias gathers
// forced an implicit full drain each iteration).
__global__ __launch_bounds__(256, 2) void attn_kernel(
    const u16* __restrict__ qb, const u16* __restrict__ kb,
    const u16* __restrict__ vtb, const u16* __restrict__ pb,
    u16* __restrict__ ao) {
  __shared__ u16 Ks[2][64 * 64];
  __shared__ u16 Vs[2][64 * 64];

  const int tid = threadIdx.x;
  const int lane = tid & 63, wave = tid >> 6;
  const int lr = lane & 15, lg = lane >> 4;
  const int bh = blockIdx.x;   // head fastest -> all q-tiles of a head on one XCD
  const int q0 = blockIdx.y * 128 + wave * 32;
  const size_t hb = (size_t)bh << 16;

  bf16x8 qf[2][2];
#pragma unroll
  for (int m = 0; m < 2; ++m)
#pragma unroll
    for (int kf = 0; kf < 2; ++kf)
      qf[m][kf] = *(const bf16x8*)(qb + hb + (size_t)(q0 + m * 16 + lr) * 64 + kf * 32 + lg * 8);

  // Preload ALL bias for this lane's two q-rows.
  // rel_h: full 32-value strip as 16 u32 words (shift register, word t = tile t)
  // rel_w: this lane's 8 kw values (kw = i*16 + lg*4 + r)
  u32 Wh[2][16];
  float rwv[2][2][4];
#pragma unroll
  for (int m = 0; m < 2; ++m) {
    int g = q0 + m * 16 + lr;
    const u16* sb = pb + (((size_t)bh << 10) + g) * 64;
    const uint4* s4 = (const uint4*)(sb + 32);
    uint4 ha = s4[0], hc = s4[1], he = s4[2], hg = s4[3];
    Wh[m][0] = ha.x;  Wh[m][1] = ha.y;  Wh[m][2] = ha.z;  Wh[m][3] = ha.w;
    Wh[m][4] = hc.x;  Wh[m][5] = hc.y;  Wh[m][6] = hc.z;  Wh[m][7] = hc.w;
    Wh[m][8] = he.x;  Wh[m][9] = he.y;  Wh[m][10] = he.z; Wh[m][11] = he.w;
    Wh[m][12] = hg.x; Wh[m][13] = hg.y; Wh[m][14] = hg.z; Wh[m][15] = hg.w;
    uint2 u0 = *(const uint2*)(sb + lg * 4);
    uint2 u1 = *(const uint2*)(sb + 16 + lg * 4);
    rwv[m][0][0] = bf2f(u0.x & 0xffffu); rwv[m][0][1] = bf2f(u0.x >> 16);
    rwv[m][0][2] = bf2f(u0.y & 0xffffu); rwv[m][0][3] = bf2f(u0.y >> 16);
    rwv[m][1][0] = bf2f(u1.x & 0xffffu); rwv[m][1][1] = bf2f(u1.x >> 16);
    rwv[m][1][2] = bf2f(u1.y & 0xffffu); rwv[m][1][3] = bf2f(u1.y >> 16);
  }

  float lsum[2] = {};
  f32x4 acco[2][4] = {};

  // loop-carried staging pointers
  const u16* kp[2];
  const u16* vp[2];
#pragma unroll
  for (int i = 0; i < 2; ++i) {
    int c = tid + i * 256;
    int row = c >> 3, pp = c & 7;
    int pl = pp ^ (row & 7);  // pre-swizzled global source, linear LDS dest
    kp[i] = kb + hb + (size_t)row * 64 + pl * 8;       // += 4096 per tile
    vp[i] = vtb + hb + (size_t)row * 1024 + pl * 8;    // += 64 per tile
  }

  auto stage = [&](int bi) {
#pragma unroll
    for (int i = 0; i < 2; ++i) {
      int c = tid + i * 256;
      GLD16(kp[i], &Ks[bi][c * 8]);
      GLD16(vp[i], &Vs[bi][c * 8]);
      kp[i] += 4096;
      vp[i] += 64;
    }
  };

  stage(0);

  const float scale2 = 0.125f * 1.44269504f;

#pragma unroll 1
  for (int t = 0; t < 16; ++t) {
    const int cur = t & 1;
    if (t < 15) {
      stage(cur ^ 1);
      asm volatile("s_waitcnt vmcnt(4)" ::: "memory");
    } else {
      asm volatile("s_waitcnt vmcnt(0)" ::: "memory");
    }
    __builtin_amdgcn_sched_barrier(0);
    __builtin_amdgcn_s_barrier();        // entry: buf[cur] ready
    __builtin_amdgcn_sched_barrier(0);

    // QK^T (swapped): sac[m][f] col=lr -> q, row=lg*4+r -> k=f*16+lg*4+r
    f32x4 sac[2][4] = {};
    __builtin_amdgcn_s_setprio(1);
#pragma unroll
    for (int kf = 0; kf < 2; ++kf) {
#pragma unroll
      for (int f = 0; f < 4; ++f) {
        int row = f * 16 + lr;
        bf16x8 kv = *(const bf16x8*)&Ks[cur][(row * 64 + kf * 32 + lg * 8) ^ ((row & 7) << 3)];
#pragma unroll
        for (int m = 0; m < 2; ++m)
          sac[m][f] = __builtin_amdgcn_mfma_f32_16x16x32_bf16(kv, qf[m][kf], sac[m][f], 0, 0, 0);
      }
    }
    __builtin_amdgcn_s_setprio(0);

    // bias + exp2 + in-register P (A-frag via kappa order, zero cross-lane)
    bf16x8 paf[2][2];
#pragma unroll
    for (int m = 0; m < 2; ++m) {
      u32 wrd = Wh[m][0];
      float c0 = bf2f(wrd & 0xffffu);   // rel_h at kh0 = 2t
      float c1 = bf2f(wrd >> 16);       // rel_h at kh0+1
      float bs[2][2][4];  // [j = b0/b1][i][r]
#pragma unroll
      for (int i = 0; i < 2; ++i)
#pragma unroll
        for (int r = 0; r < 4; ++r) {
          bs[0][i][r] = c0 + rwv[m][i][r];
          bs[1][i][r] = c1 + rwv[m][i][r];
        }
      union { u32 w[4]; bf16x8 v; } wa, wb;
#pragma unroll
      for (int f = 0; f < 4; ++f) {
        const int j = (f >> 1) & 1, i = f & 1;
        float p0 = __builtin_amdgcn_exp2f(sac[m][f][0] * scale2 + bs[j][i][0]);
        float p1 = __builtin_amdgcn_exp2f(sac[m][f][1] * scale2 + bs[j][i][1]);
        float p2 = __builtin_amdgcn_exp2f(sac[m][f][2] * scale2 + bs[j][i][2]);
        float p3 = __builtin_amdgcn_exp2f(sac[m][f][3] * scale2 + bs[j][i][3]);
        lsum[m] += (p0 + p1) + (p2 + p3);
        u32 w0, w1;
        asm("v_cvt_pk_bf16_f32 %0, %1, %2" : "=v"(w0) : "v"(p0), "v"(p1));
        asm("v_cvt_pk_bf16_f32 %0, %1, %2" : "=v"(w1) : "v"(p2), "v"(p3));
        if (f < 2) { wa.w[f * 2] = w0; wa.w[f * 2 + 1] = w1; }
        else       { wb.w[(f - 2) * 2] = w0; wb.w[(f - 2) * 2 + 1] = w1; }
      }
      paf[m][0] = wa.v;
      paf[m][1] = wb.v;
    }

    // shift bias word register down (static indices; next tile uses Wh[m][0])
#pragma unroll
    for (int k = 0; k < 15; ++k) { Wh[0][k] = Wh[0][k + 1]; Wh[1][k] = Wh[1][k + 1]; }

    // PV: O[q][d], acco row=lg*4+r -> q, col=lr -> d
    __builtin_amdgcn_s_setprio(1);
#pragma unroll
    for (int kf = 0; kf < 2; ++kf) {
#pragma unroll
      for (int fd = 0; fd < 4; ++fd) {
        int drow = fd * 16 + lr;
        bf16x8 vv = *(const bf16x8*)&Vs[cur][(drow * 64 + kf * 32 + lg * 8) ^ ((drow & 7) << 3)];
#pragma unroll
        for (int m = 0; m < 2; ++m)
          acco[m][fd] = __builtin_amdgcn_mfma_f32_16x16x32_bf16(paf[m][kf], vv, acco[m][fd], 0, 0, 0);
      }
    }
    __builtin_amdgcn_s_setprio(0);

    __builtin_amdgcn_sched_barrier(0);
    __builtin_amdgcn_s_barrier();        // exit: reads done before overwrite
    __builtin_amdgcn_sched_barrier(0);
  }

#pragma unroll
  for (int m = 0; m < 2; ++m) {
    float s = lsum[m];
    s += __shfl_xor(s, 16);
    s += __shfl_xor(s, 32);
    float inv = 1.0f / s;  // valid on lane with lr = q-local, any lg
#pragma unroll
    for (int r = 0; r < 4; ++r) {
      int src = (lane & 48) + ((lane & 48) >> 2) + r;
      float invr = __shfl(inv, src);
      int gq = q0 + m * 16 + lg * 4 + r;
#pragma unroll
      for (int fd = 0; fd < 4; ++fd)
        ao[hb + (size_t)gq * 64 + fd * 16 + lr] = f2bf(acco[m][fd][r] * invr);
    }
  }
}

// ---------------------------------------------------------------- launch
extern "C" void kernel_launch(void* const* d_in, const int* in_sizes, int n_in,
                              void* d_out, int out_size, void* d_ws, size_t ws_size,
                              hipStream_t stream) {
  const float* x = (const float*)d_in[0];
  const float* qkv_w = (const float*)d_in[1];
  const float* qkv_b = (const float*)d_in[2];
  const float* proj_w = (const float*)d_in[3];
  const float* proj_b = (const float*)d_in[4];
  const float* rel_pos_h = (const float*)d_in[5];
  const float* rel_pos_w = (const float*)d_in[6];
  float* out = (float*)d_out;

  char* ws = (char*)d_ws;
  u16* x_bf = (u16*)(ws + 0);              // 12,582,912 B (reused as attn out)
  u16* qkvw_bf = (u16*)(ws + 12582912);    //  3,538,944
  u16* projw_bf = (u16*)(ws + 16121856);   //  1,179,648
  u16* qbuf = (u16*)(ws + 17301504);       // 12,582,912
  u16* kbuf = (u16*)(ws + 29884416);       // 12,582,912
  u16* vtbuf = (u16*)(ws + 42467328);      // 12,582,912
  u16* pbuf = (u16*)(ws + 55050240);       // 12,582,912 (98304 x 64 bf16 strips)
  u16* tbl = (u16*)(ws + 80216064);        //     16,384 -> total 80,232,448
  u16* aobuf = x_bf;                        // alias: x_bf dead after QKV gemm

  cvt_kernel<<<6144, 256, 0, stream>>>(x, x_bf, 6291456);
  cvt_kernel<<<1728, 256, 0, stream>>>(qkv_w, qkvw_bf, 1769472);
  cvt_kernel<<<576, 256, 0, stream>>>(proj_w, projw_bf, 589824);
  tbl_kernel<<<32, 256, 0, stream>>>(rel_pos_h, rel_pos_w, tbl);

  gemm128<0><<<dim3(18, 64), 512, 0, stream>>>(x_bf, qkvw_bf, qkv_b, qbuf, kbuf, vtbuf, nullptr);

  pgemm_kernel<<<768, 256, 0, stream>>>(qbuf, tbl, pbuf);

  attn_kernel<<<dim3(96, 8), 256, 0, stream>>>(qbuf, kbuf, vtbuf, pbuf, aobuf);

  gemm128<1><<<dim3(6, 64), 512, 0, stream>>>(aobuf, projw_bf, proj_b, nullptr, nullptr, nullptr, out);
}

// Round 12
// 130.530 us; speedup vs baseline: 1.1154x; 1.0354x over previous
//
#include <hip/hip_runtime.h>

using u16 = unsigned short;
using u32 = unsigned int;
typedef __attribute__((ext_vector_type(8))) short bf16x8;
typedef __attribute__((ext_vector_type(4))) float f32x4;

__device__ __forceinline__ float bf2f(u32 h) {
  union { u32 u; float f; } c; c.u = h << 16; return c.f;
}
__device__ __forceinline__ u16 f2bf(float f) {
  union { float f; u32 u; } c; c.f = f;
  u32 u = c.u;
  u32 r = (u + 0x7FFFu + ((u >> 16) & 1u)) >> 16;
  return (u16)r;
}

#define GLD16(gsrc, ldst)                                                      \
  __builtin_amdgcn_global_load_lds(                                            \
      (const __attribute__((address_space(1))) unsigned int*)(gsrc),           \
      (__attribute__((address_space(3))) unsigned int*)(ldst), 16, 0, 0)

// kappa: virtual key order inside a 64-key tile so PV's A-frag is the natural
// register layout of the swapped QK^T output.
__device__ __forceinline__ int kappa(int ss) {
  return (ss & 0x23) | ((ss & 0x10) >> 2) | ((ss & 0x0C) << 1);
}

// ---------------------------------------------------------------- convert
__global__ void cvt_kernel(const float* __restrict__ src, u16* __restrict__ dst, int n) {
  int i = (blockIdx.x * blockDim.x + threadIdx.x) * 4;
  if (i < n) {
    float4 v = *(const float4*)(src + i);
    ushort4 o;
    o.x = f2bf(v.x); o.y = f2bf(v.y); o.z = f2bf(v.z); o.w = f2bf(v.w);
    *(ushort4*)(dst + i) = o;
  }
}

// ---------------------------------------------------------------- rel-pos table
// x8 (not log2e): q is pre-scaled by 0.125*log2e, and 0.125*8 = 1, so
// (q*scale2) . (raw*8) = q*raw*log2e -- strips land in log2 domain.
__global__ void tbl_kernel(const float* __restrict__ rph, const float* __restrict__ rpw,
                           u16* __restrict__ tbl) {
  int i = blockIdx.x * 256 + threadIdx.x;  // 8192 total
  int row = i >> 6, d = i & 63;
  float v = 0.f;
  if (row < 63) v = rph[row * 64 + d];
  else if (row >= 64 && row < 127) v = rpw[(row - 64) * 64 + d];
  tbl[i] = f2bf(v * 8.0f);
}

// ---------------------------------------------------------------- K augment
// kbuf2[g][64+kw(s)] = 1, kbuf2[g][96+kh(s)] = 1, rest of [64..128) = 0.
__global__ void aug_kernel(u16* __restrict__ kb) {
  int j = blockIdx.x * 256 + threadIdx.x;   // 1,572,864 quads
  int g = j >> 4, q4 = j & 15;
  int s = g & 1023;
  int d0 = 64 + q4 * 4;
  int kwslot = 64 + (s & 31);
  int khslot = 96 + (s >> 5);
  ushort4 v;
  v.x = (d0 == kwslot || d0 == khslot) ? 0x3F80 : 0;
  v.y = (d0 + 1 == kwslot || d0 + 1 == khslot) ? 0x3F80 : 0;
  v.z = (d0 + 2 == kwslot || d0 + 2 == khslot) ? 0x3F80 : 0;
  v.w = (d0 + 3 == kwslot || d0 + 3 == khslot) ? 0x3F80 : 0;
  *(ushort4*)&kb[(size_t)g * 128 + d0] = v;
}

// ---------------------------------------------------------------- P gemm
// strips = (q*scale2)[g] . tbl8[j]; scattered into the aug half of Q:
//   Q2[g][64+kw] = rel_w(g,kw), Q2[g][96+kh] = rel_h(g,kh)  (log2 domain)
__global__ __launch_bounds__(256, 2) void pgemm_kernel(
    const u16* __restrict__ A, const u16* __restrict__ tbl, u16* __restrict__ Q2) {
  __shared__ u16 As[128 * 64];
  __shared__ u16 Bs[128 * 64];
  const int tid = threadIdx.x;
  const int lane = tid & 63, wave = tid >> 6;
  const int lr = lane & 15, lg = lane >> 4;
  const int m0 = blockIdx.x * 128;
  const int wm = (wave >> 1) * 64, wn = (wave & 1) * 64;

#pragma unroll
  for (int i = 0; i < 4; ++i) {
    int c = tid + i * 256;
    int row = c >> 3, pp = c & 7;
    int pl = pp ^ (row & 7);  // pre-swizzled source, linear LDS dest
    GLD16(A + (size_t)(m0 + row) * 128 + pl * 8, &As[c * 8]);
    GLD16(tbl + row * 64 + pl * 8, &Bs[c * 8]);
  }
  __syncthreads();

  bf16x8 a[4][2], b[4][2];
#pragma unroll
  for (int m = 0; m < 4; ++m) {
    int row = wm + m * 16 + lr;
#pragma unroll
    for (int kf = 0; kf < 2; ++kf)
      a[m][kf] = *(const bf16x8*)&As[(row * 64 + kf * 32 + lg * 8) ^ ((row & 7) << 3)];
  }
#pragma unroll
  for (int n = 0; n < 4; ++n) {
    int row = wn + n * 16 + lr;
#pragma unroll
    for (int kf = 0; kf < 2; ++kf)
      b[n][kf] = *(const bf16x8*)&Bs[(row * 64 + kf * 32 + lg * 8) ^ ((row & 7) << 3)];
  }

  f32x4 acc[4][4] = {};
#pragma unroll
  for (int kf = 0; kf < 2; ++kf)
#pragma unroll
    for (int m = 0; m < 4; ++m)
#pragma unroll
      for (int n = 0; n < 4; ++n)
        acc[m][n] = __builtin_amdgcn_mfma_f32_16x16x32_bf16(a[m][kf], b[n][kf], acc[m][n], 0, 0, 0);

#pragma unroll
  for (int m = 0; m < 4; ++m)
#pragma unroll
    for (int n = 0; n < 4; ++n) {
      const int col = wn + n * 16 + lr;
#pragma unroll
      for (int r = 0; r < 4; ++r) {
        const int g = m0 + wm + m * 16 + lg * 4 + r;
        const int s = g & 1023;
        const int hq = s >> 5, w = s & 31;
        u16 hv = f2bf(acc[m][n][r]);
        if (col < 64) {
          int kh = hq + 31 - col;
          if ((unsigned)kh < 32u) Q2[(size_t)g * 128 + 96 + kh] = hv;
        } else {
          int kw = w + 95 - col;
          if ((unsigned)kw < 32u) Q2[(size_t)g * 128 + 64 + kw] = hv;
        }
      }
    }
}

// ---------------------------------------------------------------- GEMM
// 128x128 tile, BK=64, 512 threads / 8 waves (wave tile 64x32), XOR-swizzled
// LDS, XCD block swizzle, counted vmcnt, loop-carried staging pointers.
// MODE 0 q/k outputs now stride-128 (aug layout); q pre-scaled by 0.125*log2e.
template <int MODE>
__global__ __launch_bounds__(512, 2) void gemm128(
    const u16* __restrict__ A, const u16* __restrict__ B,
    const float* __restrict__ bias, u16* __restrict__ oq, u16* __restrict__ ok,
    u16* __restrict__ ovt, float* __restrict__ ofp) {
  __shared__ u16 As[2][128 * 64];
  __shared__ u16 Bs[2][128 * 64];
  const int tid = threadIdx.x;
  const int lane = tid & 63, wave = tid >> 6;
  const int lr = lane & 15, lg = lane >> 4;

  const int nbx = (MODE == 0) ? 18 : 6;
  const int nwg = nbx * 64;
  int id = blockIdx.y * nbx + blockIdx.x;
  int nid = (id & 7) * (nwg >> 3) + (id >> 3);
  const int m0 = (nid / nbx) * 128, n0 = (nid % nbx) * 128;
  const int wm = (wave >> 2) * 64, wn = (wave & 3) * 32;

  f32x4 acc[4][2] = {};

  const u16* ap[2];
  const u16* bp[2];
#pragma unroll
  for (int i = 0; i < 2; ++i) {
    int c = tid + i * 512;          // 1024 chunks = 128 rows x 8
    int row = c >> 3, pp = c & 7;
    int pl = pp ^ (row & 7);        // pre-swizzled global source, linear LDS dest
    if constexpr (MODE == 0) {
      ap[i] = A + (size_t)(m0 + row) * 768 + pl * 8;
    } else {
      int g = m0 + row;
      ap[i] = A + ((size_t)((g >> 10) * 12) << 16) + (g & 1023) * 64 + pl * 8;
    }
    bp[i] = B + (size_t)(n0 + row) * 768 + pl * 8;
  }
  constexpr int dA = (MODE == 0) ? 64 : 65536;

  auto stage = [&](int bi) {
#pragma unroll
    for (int i = 0; i < 2; ++i) {
      int c = tid + i * 512;
      GLD16(ap[i], &As[bi][c * 8]);
      GLD16(bp[i], &Bs[bi][c * 8]);
      ap[i] += dA;
      bp[i] += 64;
    }
  };

  stage(0);
#pragma unroll 1
  for (int t = 0; t < 12; ++t) {
    const int cur = t & 1;
    if (t < 11) {
      stage(cur ^ 1);
      asm volatile("s_waitcnt vmcnt(4)" ::: "memory");
    } else {
      asm volatile("s_waitcnt vmcnt(0)" ::: "memory");
    }
    __builtin_amdgcn_sched_barrier(0);
    __builtin_amdgcn_s_barrier();        // entry: buf[cur] ready for all waves
    __builtin_amdgcn_sched_barrier(0);

    bf16x8 a[4][2], b[2][2];
#pragma unroll
    for (int m = 0; m < 4; ++m) {
      int row = wm + m * 16 + lr;
#pragma unroll
      for (int kf = 0; kf < 2; ++kf)
        a[m][kf] = *(const bf16x8*)&As[cur][(row * 64 + kf * 32 + lg * 8) ^ ((row & 7) << 3)];
    }
#pragma unroll
    for (int n = 0; n < 2; ++n) {
      int row = wn + n * 16 + lr;
#pragma unroll
      for (int kf = 0; kf < 2; ++kf)
        b[n][kf] = *(const bf16x8*)&Bs[cur][(row * 64 + kf * 32 + lg * 8) ^ ((row & 7) << 3)];
    }
    __builtin_amdgcn_s_setprio(1);
#pragma unroll
    for (int kf = 0; kf < 2; ++kf)
#pragma unroll
      for (int m = 0; m < 4; ++m)
#pragma unroll
        for (int n = 0; n < 2; ++n)
          acc[m][n] = __builtin_amdgcn_mfma_f32_16x16x32_bf16(a[m][kf], b[n][kf], acc[m][n], 0, 0, 0);
    __builtin_amdgcn_s_setprio(0);

    __builtin_amdgcn_sched_barrier(0);
    __builtin_amdgcn_s_barrier();        // exit: all reads done before overwrite
    __builtin_amdgcn_sched_barrier(0);
  }

#pragma unroll
  for (int m = 0; m < 4; ++m) {
    const int grow0 = m0 + wm + m * 16 + lg * 4;
#pragma unroll
    for (int n = 0; n < 2; ++n) {
      const int gcol = n0 + wn + n * 16 + lr;
      const float bv = bias[gcol];
      if constexpr (MODE == 0) {
        int which = (gcol >= 1536) ? 2 : (gcol >= 768 ? 1 : 0);
        int rem = gcol - which * 768;
        int bh = (grow0 >> 10) * 12 + (rem >> 6);
        if (which == 2) {
          int s0 = grow0 & 1023;
          int colb = (s0 & ~63) | kappa(s0 & 63);  // kappa keeps low 2 bits
          ushort4 pk;
          pk.x = f2bf(acc[m][n][0] + bv);
          pk.y = f2bf(acc[m][n][1] + bv);
          pk.z = f2bf(acc[m][n][2] + bv);
          pk.w = f2bf(acc[m][n][3] + bv);
          *(ushort4*)&ovt[((size_t)bh << 16) + (size_t)(rem & 63) * 1024 + colb] = pk;
        } else {
          u16* dst = (which == 0) ? oq : ok;
          const float sc = (which == 0) ? 0.18033688f : 1.0f;  // 0.125*log2e
#pragma unroll
          for (int r = 0; r < 4; ++r) {
            int s = (grow0 & 1023) + r;
            dst[((size_t)bh << 17) + s * 128 + (rem & 63)] = f2bf((acc[m][n][r] + bv) * sc);
          }
        }
      } else {
#pragma unroll
        for (int r = 0; r < 4; ++r)
          ofp[(size_t)(grow0 + r) * 768 + gcol] = acc[m][n][r] + bv;
      }
    }
  }
}

// ---------------------------------------------------------------- flash attention
// grid (96 heads, 8 q-tiles); block 256 = 4 waves x 32 q-rows.
// Augmented QK^T: d=128 with Q=[q*scale2; rw-strip; rh-strip] and
// K=[k; onehot(kw); onehot(kh)] -> sac IS the final logit (log2 domain).
// Softmax = exp2 + sum + pack only. Swapped operands + kappa V as before.
__global__ __launch_bounds__(256, 2) void attn_kernel(
    const u16* __restrict__ qb, const u16* __restrict__ kb,
    const u16* __restrict__ vtb, u16* __restrict__ ao) {
  __shared__ u16 Ks[2][8192];   // two 64x64 swizzled halves per buffer
  __shared__ u16 Vs[2][4096];

  const int tid = threadIdx.x;
  const int lane = tid & 63, wave = tid >> 6;
  const int lr = lane & 15, lg = lane >> 4;
  const int bh = blockIdx.x;   // head fastest -> all q-tiles of a head on one XCD
  const int q0 = blockIdx.y * 128 + wave * 32;
  const size_t hb2 = (size_t)bh << 17;   // q,k stride-128 region
  const size_t hbv = (size_t)bh << 16;   // v^T / output stride-64 region

  bf16x8 qf[2][4];
#pragma unroll
  for (int m = 0; m < 2; ++m)
#pragma unroll
    for (int kf = 0; kf < 4; ++kf)
      qf[m][kf] = *(const bf16x8*)(qb + hb2 + (size_t)(q0 + m * 16 + lr) * 128 + kf * 32 + lg * 8);

  float lsum[2] = {};
  f32x4 acco[2][4] = {};

  // loop-carried staging pointers: K = 4 chunks (two 64-wide halves), V = 2
  const u16* kp[4];
  const u16* vp[2];
#pragma unroll
  for (int i = 0; i < 4; ++i) {
    int c = tid + i * 256;
    int half = c >> 9, row = (c >> 3) & 63, pp = c & 7;
    int pl = pp ^ (row & 7);  // pre-swizzled global source, linear LDS dest
    kp[i] = kb + hb2 + (size_t)row * 128 + half * 64 + pl * 8;   // += 8192/tile
  }
#pragma unroll
  for (int i = 0; i < 2; ++i) {
    int c = tid + i * 256;
    int row = c >> 3, pp = c & 7;
    int pl = pp ^ (row & 7);
    vp[i] = vtb + hbv + (size_t)row * 1024 + pl * 8;             // += 64/tile
  }

  auto stage = [&](int bi) {
#pragma unroll
    for (int i = 0; i < 4; ++i) {
      int c = tid + i * 256;
      GLD16(kp[i], &Ks[bi][c * 8]);
      kp[i] += 8192;
    }
#pragma unroll
    for (int i = 0; i < 2; ++i) {
      int c = tid + i * 256;
      GLD16(vp[i], &Vs[bi][c * 8]);
      vp[i] += 64;
    }
  };

  stage(0);

#pragma unroll 1
  for (int t = 0; t < 16; ++t) {
    const int cur = t & 1;
    if (t < 15) {
      stage(cur ^ 1);
      asm volatile("s_waitcnt vmcnt(6)" ::: "memory");
    } else {
      asm volatile("s_waitcnt vmcnt(0)" ::: "memory");
    }
    __builtin_amdgcn_sched_barrier(0);
    __builtin_amdgcn_s_barrier();        // entry: buf[cur] ready
    __builtin_amdgcn_sched_barrier(0);

    // QK^T over d=128: sac[m][f] col=lr -> q, row=lg*4+r -> k=f*16+lg*4+r
    f32x4 sac[2][4] = {};
    __builtin_amdgcn_s_setprio(1);
#pragma unroll
    for (int kf = 0; kf < 4; ++kf) {
      const int half = kf >> 1, kfl = kf & 1;
#pragma unroll
      for (int f = 0; f < 4; ++f) {
        int row = f * 16 + lr;
        bf16x8 kv = *(const bf16x8*)&Ks[cur][half * 4096 +
            ((row * 64 + kfl * 32 + lg * 8) ^ ((row & 7) << 3))];
#pragma unroll
        for (int m = 0; m < 2; ++m)
          sac[m][f] = __builtin_amdgcn_mfma_f32_16x16x32_bf16(kv, qf[m][kf], sac[m][f], 0, 0, 0);
      }
    }
    __builtin_amdgcn_s_setprio(0);

    // softmax: logits are ready -- exp2 + deferred sum + packed bf16 (kappa)
    bf16x8 paf[2][2];
#pragma unroll
    for (int m = 0; m < 2; ++m) {
      union { u32 w[4]; bf16x8 v; } wa, wb;
#pragma unroll
      for (int f = 0; f < 4; ++f) {
        float p0 = __builtin_amdgcn_exp2f(sac[m][f][0]);
        float p1 = __builtin_amdgcn_exp2f(sac[m][f][1]);
        float p2 = __builtin_amdgcn_exp2f(sac[m][f][2]);
        float p3 = __builtin_amdgcn_exp2f(sac[m][f][3]);
        lsum[m] += (p0 + p1) + (p2 + p3);
        u32 w0, w1;
        asm("v_cvt_pk_bf16_f32 %0, %1, %2" : "=v"(w0) : "v"(p0), "v"(p1));
        asm("v_cvt_pk_bf16_f32 %0, %1, %2" : "=v"(w1) : "v"(p2), "v"(p3));
        if (f < 2) { wa.w[f * 2] = w0; wa.w[f * 2 + 1] = w1; }
        else       { wb.w[(f - 2) * 2] = w0; wb.w[(f - 2) * 2 + 1] = w1; }
      }
      paf[m][0] = wa.v;
      paf[m][1] = wb.v;
    }

    // PV: O[q][d], acco row=lg*4+r -> q, col=lr -> d
    __builtin_amdgcn_s_setprio(1);
#pragma unroll
    for (int kf = 0; kf < 2; ++kf) {
#pragma unroll
      for (int fd = 0; fd < 4; ++fd) {
        int drow = fd * 16 + lr;
        bf16x8 vv = *(const bf16x8*)&Vs[cur][(drow * 64 + kf * 32 + lg * 8) ^ ((drow & 7) << 3)];
#pragma unroll
        for (int m = 0; m < 2; ++m)
          acco[m][fd] = __builtin_amdgcn_mfma_f32_16x16x32_bf16(paf[m][kf], vv, acco[m][fd], 0, 0, 0);
      }
    }
    __builtin_amdgcn_s_setprio(0);

    __builtin_amdgcn_sched_barrier(0);
    __builtin_amdgcn_s_barrier();        // exit: reads done before overwrite
    __builtin_amdgcn_sched_barrier(0);
  }

#pragma unroll
  for (int m = 0; m < 2; ++m) {
    float s = lsum[m];
    s += __shfl_xor(s, 16);
    s += __shfl_xor(s, 32);
    float inv = 1.0f / s;  // valid on lane with lr = q-local, any lg
#pragma unroll
    for (int r = 0; r < 4; ++r) {
      int src = (lane & 48) + ((lane & 48) >> 2) + r;
      float invr = __shfl(inv, src);
      int gq = q0 + m * 16 + lg * 4 + r;
#pragma unroll
      for (int fd = 0; fd < 4; ++fd)
        ao[hbv + (size_t)gq * 64 + fd * 16 + lr] = f2bf(acco[m][fd][r] * invr);
    }
  }
}

// ---------------------------------------------------------------- launch
extern "C" void kernel_launch(void* const* d_in, const int* in_sizes, int n_in,
                              void* d_out, int out_size, void* d_ws, size_t ws_size,
                              hipStream_t stream) {
  const float* x = (const float*)d_in[0];
  const float* qkv_w = (const float*)d_in[1];
  const float* qkv_b = (const float*)d_in[2];
  const float* proj_w = (const float*)d_in[3];
  const float* proj_b = (const float*)d_in[4];
  const float* rel_pos_h = (const float*)d_in[5];
  const float* rel_pos_w = (const float*)d_in[6];
  float* out = (float*)d_out;

  char* ws = (char*)d_ws;
  u16* x_bf = (u16*)(ws + 0);              // 12,582,912 B (reused as attn out)
  u16* qkvw_bf = (u16*)(ws + 12582912);    //  3,538,944
  u16* projw_bf = (u16*)(ws + 16121856);   //  1,179,648
  u16* qbuf2 = (u16*)(ws + 17301504);      // 25,165,824 (96x1024x128, aug Q)
  u16* kbuf2 = (u16*)(ws + 42467328);      // 25,165,824 (96x1024x128, aug K)
  u16* vtbuf = (u16*)(ws + 67633152);      // 12,582,912
  u16* tbl = (u16*)(ws + 80216064);        //     16,384 -> total 80,232,448
  u16* aobuf = x_bf;                        // alias: x_bf dead after QKV gemm

  cvt_kernel<<<6144, 256, 0, stream>>>(x, x_bf, 6291456);
  cvt_kernel<<<1728, 256, 0, stream>>>(qkv_w, qkvw_bf, 1769472);
  cvt_kernel<<<576, 256, 0, stream>>>(proj_w, projw_bf, 589824);
  tbl_kernel<<<32, 256, 0, stream>>>(rel_pos_h, rel_pos_w, tbl);
  aug_kernel<<<6144, 256, 0, stream>>>(kbuf2);

  gemm128<0><<<dim3(18, 64), 512, 0, stream>>>(x_bf, qkvw_bf, qkv_b, qbuf2, kbuf2, vtbuf, nullptr);

  pgemm_kernel<<<768, 256, 0, stream>>>(qbuf2, tbl, qbuf2);

  attn_kernel<<<dim3(96, 8), 256, 0, stream>>>(qbuf2, kbuf2, vtbuf, aobuf);

  gemm128<1><<<dim3(6, 64), 512, 0, stream>>>(aobuf, projw_bf, proj_b, nullptr, nullptr, nullptr, out);
}

// Round 13
// 124.605 us; speedup vs baseline: 1.1684x; 1.0476x over previous
//
#include <hip/hip_runtime.h>

using u16 = unsigned short;
using u32 = unsigned int;
typedef __attribute__((ext_vector_type(8))) short bf16x8;
typedef __attribute__((ext_vector_type(4))) float f32x4;

__device__ __forceinline__ float bf2f(u32 h) {
  union { u32 u; float f; } c; c.u = h << 16; return c.f;
}
__device__ __forceinline__ u16 f2bf(float f) {
  union { float f; u32 u; } c; c.f = f;
  u32 u = c.u;
  u32 r = (u + 0x7FFFu + ((u >> 16) & 1u)) >> 16;
  return (u16)r;
}

#define GLD16(gsrc, ldst)                                                      \
  __builtin_amdgcn_global_load_lds(                                            \
      (const __attribute__((address_space(1))) unsigned int*)(gsrc),           \
      (__attribute__((address_space(3))) unsigned int*)(ldst), 16, 0, 0)

// kappa: virtual key order inside a 64-key tile so PV's A-frag is the natural
// register layout of the swapped QK^T output.
__device__ __forceinline__ int kappa(int ss) {
  return (ss & 0x23) | ((ss & 0x10) >> 2) | ((ss & 0x0C) << 1);
}

// one-hot bf16x8 A-frag word builder: hot halfword c in [0,8), zero otherwise
__device__ __forceinline__ bf16x8 onehot8(int c) {
  union { u32 w[4]; bf16x8 v; } u;
  u32 hv = (c & 1) ? 0x3F800000u : 0x3F80u;
#pragma unroll
  for (int k = 0; k < 4; ++k) u.w[k] = ((c >> 1) == k) ? hv : 0u;
  return u.v;
}

// ---------------------------------------------------------------- convert
__global__ void cvt_kernel(const float* __restrict__ src, u16* __restrict__ dst, int n) {
  int i = (blockIdx.x * blockDim.x + threadIdx.x) * 4;
  if (i < n) {
    float4 v = *(const float4*)(src + i);
    ushort4 o;
    o.x = f2bf(v.x); o.y = f2bf(v.y); o.z = f2bf(v.z); o.w = f2bf(v.w);
    *(ushort4*)(dst + i) = o;
  }
}

// ---------------------------------------------------------------- rel-pos table
// x8 (not log2e): q is pre-scaled by 0.125*log2e, and 0.125*8 = 1, so
// (q*scale2) . (raw*8) = q*raw*log2e -- strips land in log2 domain.
__global__ void tbl_kernel(const float* __restrict__ rph, const float* __restrict__ rpw,
                           u16* __restrict__ tbl) {
  int i = blockIdx.x * 256 + threadIdx.x;  // 8192 total
  int row = i >> 6, d = i & 63;
  float v = 0.f;
  if (row < 63) v = rph[row * 64 + d];
  else if (row >= 64 && row < 127) v = rpw[(row - 64) * 64 + d];
  tbl[i] = f2bf(v * 8.0f);
}

// ---------------------------------------------------------------- P gemm
// strips = (q*scale2)[g] . tbl8[j]; scattered into the aug half of Q:
//   Q2[g][64+kw] = rel_w(g,kw), Q2[g][96+kh] = rel_h(g,kh)  (log2 domain)
__global__ __launch_bounds__(256, 2) void pgemm_kernel(
    const u16* __restrict__ A, const u16* __restrict__ tbl, u16* __restrict__ Q2) {
  __shared__ u16 As[128 * 64];
  __shared__ u16 Bs[128 * 64];
  const int tid = threadIdx.x;
  const int lane = tid & 63, wave = tid >> 6;
  const int lr = lane & 15, lg = lane >> 4;
  const int m0 = blockIdx.x * 128;
  const int wm = (wave >> 1) * 64, wn = (wave & 1) * 64;

#pragma unroll
  for (int i = 0; i < 4; ++i) {
    int c = tid + i * 256;
    int row = c >> 3, pp = c & 7;
    int pl = pp ^ (row & 7);  // pre-swizzled source, linear LDS dest
    GLD16(A + (size_t)(m0 + row) * 128 + pl * 8, &As[c * 8]);
    GLD16(tbl + row * 64 + pl * 8, &Bs[c * 8]);
  }
  __syncthreads();

  bf16x8 a[4][2], b[4][2];
#pragma unroll
  for (int m = 0; m < 4; ++m) {
    int row = wm + m * 16 + lr;
#pragma unroll
    for (int kf = 0; kf < 2; ++kf)
      a[m][kf] = *(const bf16x8*)&As[(row * 64 + kf * 32 + lg * 8) ^ ((row & 7) << 3)];
  }
#pragma unroll
  for (int n = 0; n < 4; ++n) {
    int row = wn + n * 16 + lr;
#pragma unroll
    for (int kf = 0; kf < 2; ++kf)
      b[n][kf] = *(const bf16x8*)&Bs[(row * 64 + kf * 32 + lg * 8) ^ ((row & 7) << 3)];
  }

  f32x4 acc[4][4] = {};
#pragma unroll
  for (int kf = 0; kf < 2; ++kf)
#pragma unroll
    for (int m = 0; m < 4; ++m)
#pragma unroll
      for (int n = 0; n < 4; ++n)
        acc[m][n] = __builtin_amdgcn_mfma_f32_16x16x32_bf16(a[m][kf], b[n][kf], acc[m][n], 0, 0, 0);

#pragma unroll
  for (int m = 0; m < 4; ++m)
#pragma unroll
    for (int n = 0; n < 4; ++n) {
      const int col = wn + n * 16 + lr;
#pragma unroll
      for (int r = 0; r < 4; ++r) {
        const int g = m0 + wm + m * 16 + lg * 4 + r;
        const int s = g & 1023;
        const int hq = s >> 5, w = s & 31;
        u16 hv = f2bf(acc[m][n][r]);
        if (col < 64) {
          int kh = hq + 31 - col;
          if ((unsigned)kh < 32u) Q2[(size_t)g * 128 + 96 + kh] = hv;
        } else {
          int kw = w + 95 - col;
          if ((unsigned)kw < 32u) Q2[(size_t)g * 128 + 64 + kw] = hv;
        }
      }
    }
}

// ---------------------------------------------------------------- GEMM
// 128x128 tile, BK=64, 512 threads / 8 waves (wave tile 64x32), XOR-swizzled
// LDS, XCD block swizzle, counted vmcnt, loop-carried staging pointers.
// MODE 0: q stride-128 (aug, pre-scaled 0.125*log2e); k stride-64; v^T kappa.
template <int MODE>
__global__ __launch_bounds__(512, 2) void gemm128(
    const u16* __restrict__ A, const u16* __restrict__ B,
    const float* __restrict__ bias, u16* __restrict__ oq, u16* __restrict__ ok,
    u16* __restrict__ ovt, float* __restrict__ ofp) {
  __shared__ u16 As[2][128 * 64];
  __shared__ u16 Bs[2][128 * 64];
  const int tid = threadIdx.x;
  const int lane = tid & 63, wave = tid >> 6;
  const int lr = lane & 15, lg = lane >> 4;

  const int nbx = (MODE == 0) ? 18 : 6;
  const int nwg = nbx * 64;
  int id = blockIdx.y * nbx + blockIdx.x;
  int nid = (id & 7) * (nwg >> 3) + (id >> 3);
  const int m0 = (nid / nbx) * 128, n0 = (nid % nbx) * 128;
  const int wm = (wave >> 2) * 64, wn = (wave & 3) * 32;

  f32x4 acc[4][2] = {};

  const u16* ap[2];
  const u16* bp[2];
#pragma unroll
  for (int i = 0; i < 2; ++i) {
    int c = tid + i * 512;          // 1024 chunks = 128 rows x 8
    int row = c >> 3, pp = c & 7;
    int pl = pp ^ (row & 7);        // pre-swizzled global source, linear LDS dest
    if constexpr (MODE == 0) {
      ap[i] = A + (size_t)(m0 + row) * 768 + pl * 8;
    } else {
      int g = m0 + row;
      ap[i] = A + ((size_t)((g >> 10) * 12) << 16) + (g & 1023) * 64 + pl * 8;
    }
    bp[i] = B + (size_t)(n0 + row) * 768 + pl * 8;
  }
  constexpr int dA = (MODE == 0) ? 64 : 65536;

  auto stage = [&](int bi) {
#pragma unroll
    for (int i = 0; i < 2; ++i) {
      int c = tid + i * 512;
      GLD16(ap[i], &As[bi][c * 8]);
      GLD16(bp[i], &Bs[bi][c * 8]);
      ap[i] += dA;
      bp[i] += 64;
    }
  };

  stage(0);
#pragma unroll 1
  for (int t = 0; t < 12; ++t) {
    const int cur = t & 1;
    if (t < 11) {
      stage(cur ^ 1);
      asm volatile("s_waitcnt vmcnt(4)" ::: "memory");
    } else {
      asm volatile("s_waitcnt vmcnt(0)" ::: "memory");
    }
    __builtin_amdgcn_sched_barrier(0);
    __builtin_amdgcn_s_barrier();        // entry: buf[cur] ready for all waves
    __builtin_amdgcn_sched_barrier(0);

    bf16x8 a[4][2], b[2][2];
#pragma unroll
    for (int m = 0; m < 4; ++m) {
      int row = wm + m * 16 + lr;
#pragma unroll
      for (int kf = 0; kf < 2; ++kf)
        a[m][kf] = *(const bf16x8*)&As[cur][(row * 64 + kf * 32 + lg * 8) ^ ((row & 7) << 3)];
    }
#pragma unroll
    for (int n = 0; n < 2; ++n) {
      int row = wn + n * 16 + lr;
#pragma unroll
      for (int kf = 0; kf < 2; ++kf)
        b[n][kf] = *(const bf16x8*)&Bs[cur][(row * 64 + kf * 32 + lg * 8) ^ ((row & 7) << 3)];
    }
    __builtin_amdgcn_s_setprio(1);
#pragma unroll
    for (int kf = 0; kf < 2; ++kf)
#pragma unroll
      for (int m = 0; m < 4; ++m)
#pragma unroll
        for (int n = 0; n < 2; ++n)
          acc[m][n] = __builtin_amdgcn_mfma_f32_16x16x32_bf16(a[m][kf], b[n][kf], acc[m][n], 0, 0, 0);
    __builtin_amdgcn_s_setprio(0);

    __builtin_amdgcn_sched_barrier(0);
    __builtin_amdgcn_s_barrier();        // exit: all reads done before overwrite
    __builtin_amdgcn_sched_barrier(0);
  }

#pragma unroll
  for (int m = 0; m < 4; ++m) {
    const int grow0 = m0 + wm + m * 16 + lg * 4;
#pragma unroll
    for (int n = 0; n < 2; ++n) {
      const int gcol = n0 + wn + n * 16 + lr;
      const float bv = bias[gcol];
      if constexpr (MODE == 0) {
        int which = (gcol >= 1536) ? 2 : (gcol >= 768 ? 1 : 0);
        int rem = gcol - which * 768;
        int bh = (grow0 >> 10) * 12 + (rem >> 6);
        if (which == 2) {
          int s0 = grow0 & 1023;
          int colb = (s0 & ~63) | kappa(s0 & 63);  // kappa keeps low 2 bits
          ushort4 pk;
          pk.x = f2bf(acc[m][n][0] + bv);
          pk.y = f2bf(acc[m][n][1] + bv);
          pk.z = f2bf(acc[m][n][2] + bv);
          pk.w = f2bf(acc[m][n][3] + bv);
          *(ushort4*)&ovt[((size_t)bh << 16) + (size_t)(rem & 63) * 1024 + colb] = pk;
        } else if (which == 0) {
          // q: aug layout stride 128, pre-scaled into log2 domain
#pragma unroll
          for (int r = 0; r < 4; ++r) {
            int s = (grow0 & 1023) + r;
            oq[((size_t)bh << 17) + s * 128 + (rem & 63)] =
                f2bf((acc[m][n][r] + bv) * 0.18033688f);
          }
        } else {
          // k: plain stride-64 layout
#pragma unroll
          for (int r = 0; r < 4; ++r) {
            int s = (grow0 & 1023) + r;
            ok[((size_t)bh << 16) + s * 64 + (rem & 63)] = f2bf(acc[m][n][r] + bv);
          }
        }
      } else {
#pragma unroll
        for (int r = 0; r < 4; ++r)
          ofp[(size_t)(grow0 + r) * 768 + gcol] = acc[m][n][r] + bv;
      }
    }
  }
}

// ---------------------------------------------------------------- flash attention
// grid (96 heads, 8 q-tiles); block 256 = 4 waves x 32 q-rows.
// Augmented QK^T with REGISTER-SYNTHESIZED one-hot K-frags: only the real
// 64-wide K is staged in LDS; the aug half's A-operand fragments are built
// analytically (kw hot at (f&1)*16+lr, t-independent; kh hot at 2t+(f>>1)).
// sac IS the final logit (log2 domain); softmax = exp2 + sum + pack.
__global__ __launch_bounds__(256, 2) void attn_kernel(
    const u16* __restrict__ qb, const u16* __restrict__ kb,
    const u16* __restrict__ vtb, u16* __restrict__ ao) {
  __shared__ u16 Ks[2][4096];
  __shared__ u16 Vs[2][4096];

  const int tid = threadIdx.x;
  const int lane = tid & 63, wave = tid >> 6;
  const int lr = lane & 15, lg = lane >> 4;
  const int bh = blockIdx.x;   // head fastest -> all q-tiles of a head on one XCD
  const int q0 = blockIdx.y * 128 + wave * 32;
  const size_t hb2 = (size_t)bh << 17;   // q stride-128 region
  const size_t hbv = (size_t)bh << 16;   // k / v^T / output stride-64 region

  bf16x8 qf[2][4];
#pragma unroll
  for (int m = 0; m < 2; ++m)
#pragma unroll
    for (int kf = 0; kf < 4; ++kf)
      qf[m][kf] = *(const bf16x8*)(qb + hb2 + (size_t)(q0 + m * 16 + lr) * 128 + kf * 32 + lg * 8);

  // kw one-hot A-frags (t-independent): hot col (f&1)*16+lr within [0,32),
  // lane's window lg*8+[0,8)
  bf16x8 kwf[2];
#pragma unroll
  for (int h = 0; h < 2; ++h) kwf[h] = onehot8(h * 16 + lr - lg * 8);

  float lsum[2] = {};
  f32x4 acco[2][4] = {};

  // loop-carried staging pointers
  const u16* kp[2];
  const u16* vp[2];
#pragma unroll
  for (int i = 0; i < 2; ++i) {
    int c = tid + i * 256;
    int row = c >> 3, pp = c & 7;
    int pl = pp ^ (row & 7);  // pre-swizzled global source, linear LDS dest
    kp[i] = kb + hbv + (size_t)row * 64 + pl * 8;       // += 4096 per tile
    vp[i] = vtb + hbv + (size_t)row * 1024 + pl * 8;    // += 64 per tile
  }

  auto stage = [&](int bi) {
#pragma unroll
    for (int i = 0; i < 2; ++i) {
      int c = tid + i * 256;
      GLD16(kp[i], &Ks[bi][c * 8]);
      GLD16(vp[i], &Vs[bi][c * 8]);
      kp[i] += 4096;
      vp[i] += 64;
    }
  };

  stage(0);

#pragma unroll 1
  for (int t = 0; t < 16; ++t) {
    const int cur = t & 1;
    if (t < 15) {
      stage(cur ^ 1);
      asm volatile("s_waitcnt vmcnt(4)" ::: "memory");
    } else {
      asm volatile("s_waitcnt vmcnt(0)" ::: "memory");
    }
    __builtin_amdgcn_sched_barrier(0);
    __builtin_amdgcn_s_barrier();        // entry: buf[cur] ready
    __builtin_amdgcn_sched_barrier(0);

    // kh one-hot A-frags for this tile: hot col 2t+h within [0,32)
    bf16x8 khf[2];
#pragma unroll
    for (int h = 0; h < 2; ++h) khf[h] = onehot8(2 * t + h - lg * 8);

    // QK^T: d=0..63 from LDS, d=64..127 from register one-hots
    f32x4 sac[2][4] = {};
    __builtin_amdgcn_s_setprio(1);
#pragma unroll
    for (int kf = 0; kf < 2; ++kf) {
#pragma unroll
      for (int f = 0; f < 4; ++f) {
        int row = f * 16 + lr;
        bf16x8 kv = *(const bf16x8*)&Ks[cur][(row * 64 + kf * 32 + lg * 8) ^ ((row & 7) << 3)];
#pragma unroll
        for (int m = 0; m < 2; ++m)
          sac[m][f] = __builtin_amdgcn_mfma_f32_16x16x32_bf16(kv, qf[m][kf], sac[m][f], 0, 0, 0);
      }
    }
#pragma unroll
    for (int f = 0; f < 4; ++f)
#pragma unroll
      for (int m = 0; m < 2; ++m)
        sac[m][f] = __builtin_amdgcn_mfma_f32_16x16x32_bf16(kwf[f & 1], qf[m][2], sac[m][f], 0, 0, 0);
#pragma unroll
    for (int f = 0; f < 4; ++f)
#pragma unroll
      for (int m = 0; m < 2; ++m)
        sac[m][f] = __builtin_amdgcn_mfma_f32_16x16x32_bf16(khf[f >> 1], qf[m][3], sac[m][f], 0, 0, 0);
    __builtin_amdgcn_s_setprio(0);

    // softmax: exp2 + deferred sum + packed bf16 (kappa order)
    bf16x8 paf[2][2];
#pragma unroll
    for (int m = 0; m < 2; ++m) {
      union { u32 w[4]; bf16x8 v; } wa, wb;
#pragma unroll
      for (int f = 0; f < 4; ++f) {
        float p0 = __builtin_amdgcn_exp2f(sac[m][f][0]);
        float p1 = __builtin_amdgcn_exp2f(sac[m][f][1]);
        float p2 = __builtin_amdgcn_exp2f(sac[m][f][2]);
        float p3 = __builtin_amdgcn_exp2f(sac[m][f][3]);
        lsum[m] += (p0 + p1) + (p2 + p3);
        u32 w0, w1;
        asm("v_cvt_pk_bf16_f32 %0, %1, %2" : "=v"(w0) : "v"(p0), "v"(p1));
        asm("v_cvt_pk_bf16_f32 %0, %1, %2" : "=v"(w1) : "v"(p2), "v"(p3));
        if (f < 2) { wa.w[f * 2] = w0; wa.w[f * 2 + 1] = w1; }
        else       { wb.w[(f - 2) * 2] = w0; wb.w[(f - 2) * 2 + 1] = w1; }
      }
      paf[m][0] = wa.v;
      paf[m][1] = wb.v;
    }

    // PV: O[q][d], acco row=lg*4+r -> q, col=lr -> d
    __builtin_amdgcn_s_setprio(1);
#pragma unroll
    for (int kf = 0; kf < 2; ++kf) {
#pragma unroll
      for (int fd = 0; fd < 4; ++fd) {
        int drow = fd * 16 + lr;
        bf16x8 vv = *(const bf16x8*)&Vs[cur][(drow * 64 + kf * 32 + lg * 8) ^ ((drow & 7) << 3)];
#pragma unroll
        for (int m = 0; m < 2; ++m)
          acco[m][fd] = __builtin_amdgcn_mfma_f32_16x16x32_bf16(paf[m][kf], vv, acco[m][fd], 0, 0, 0);
      }
    }
    __builtin_amdgcn_s_setprio(0);

    __builtin_amdgcn_sched_barrier(0);
    __builtin_amdgcn_s_barrier();        // exit: reads done before overwrite
    __builtin_amdgcn_sched_barrier(0);
  }

#pragma unroll
  for (int m = 0; m < 2; ++m) {
    float s = lsum[m];
    s += __shfl_xor(s, 16);
    s += __shfl_xor(s, 32);
    float inv = 1.0f / s;  // valid on lane with lr = q-local, any lg
#pragma unroll
    for (int r = 0; r < 4; ++r) {
      int src = (lane & 48) + ((lane & 48) >> 2) + r;
      float invr = __shfl(inv, src);
      int gq = q0 + m * 16 + lg * 4 + r;
#pragma unroll
      for (int fd = 0; fd < 4; ++fd)
        ao[hbv + (size_t)gq * 64 + fd * 16 + lr] = f2bf(acco[m][fd][r] * invr);
    }
  }
}

// ---------------------------------------------------------------- launch
extern "C" void kernel_launch(void* const* d_in, const int* in_sizes, int n_in,
                              void* d_out, int out_size, void* d_ws, size_t ws_size,
                              hipStream_t stream) {
  const float* x = (const float*)d_in[0];
  const float* qkv_w = (const float*)d_in[1];
  const float* qkv_b = (const float*)d_in[2];
  const float* proj_w = (const float*)d_in[3];
  const float* proj_b = (const float*)d_in[4];
  const float* rel_pos_h = (const float*)d_in[5];
  const float* rel_pos_w = (const float*)d_in[6];
  float* out = (float*)d_out;

  char* ws = (char*)d_ws;
  u16* x_bf = (u16*)(ws + 0);              // 12,582,912 B (reused as attn out)
  u16* qkvw_bf = (u16*)(ws + 12582912);    //  3,538,944
  u16* projw_bf = (u16*)(ws + 16121856);   //  1,179,648
  u16* qbuf2 = (u16*)(ws + 17301504);      // 25,165,824 (96x1024x128, aug Q)
  u16* kbuf = (u16*)(ws + 42467328);       // 12,582,912 (96x1024x64)
  u16* vtbuf = (u16*)(ws + 55050240);      // 12,582,912
  u16* tbl = (u16*)(ws + 67633152);        //     16,384 -> total 67,649,536
  u16* aobuf = x_bf;                        // alias: x_bf dead after QKV gemm

  cvt_kernel<<<6144, 256, 0, stream>>>(x, x_bf, 6291456);
  cvt_kernel<<<1728, 256, 0, stream>>>(qkv_w, qkvw_bf, 1769472);
  cvt_kernel<<<576, 256, 0, stream>>>(proj_w, projw_bf, 589824);
  tbl_kernel<<<32, 256, 0, stream>>>(rel_pos_h, rel_pos_w, tbl);

  gemm128<0><<<dim3(18, 64), 512, 0, stream>>>(x_bf, qkvw_bf, qkv_b, qbuf2, kbuf, vtbuf, nullptr);

  pgemm_kernel<<<768, 256, 0, stream>>>(qbuf2, tbl, qbuf2);

  attn_kernel<<<dim3(96, 8), 256, 0, stream>>>(qbuf2, kbuf, vtbuf, aobuf);

  gemm128<1><<<dim3(6, 64), 512, 0, stream>>>(aobuf, projw_bf, proj_b, nullptr, nullptr, nullptr, out);
}

// Round 14
// 120.498 us; speedup vs baseline: 1.2083x; 1.0341x over previous
//
#include <hip/hip_runtime.h>

using u16 = unsigned short;
using u32 = unsigned int;
typedef __attribute__((ext_vector_type(8))) short bf16x8;
typedef __attribute__((ext_vector_type(4))) float f32x4;

__device__ __forceinline__ float bf2f(u32 h) {
  union { u32 u; float f; } c; c.u = h << 16; return c.f;
}
__device__ __forceinline__ u16 f2bf(float f) {
  union { float f; u32 u; } c; c.f = f;
  u32 u = c.u;
  u32 r = (u + 0x7FFFu + ((u >> 16) & 1u)) >> 16;
  return (u16)r;
}

#define GLD16(gsrc, ldst)                                                      \
  __builtin_amdgcn_global_load_lds(                                            \
      (const __attribute__((address_space(1))) unsigned int*)(gsrc),           \
      (__attribute__((address_space(3))) unsigned int*)(ldst), 16, 0, 0)

// kappa: virtual key order inside a 64-key tile so PV's A-frag is the natural
// register layout of the swapped QK^T output.
__device__ __forceinline__ int kappa(int ss) {
  return (ss & 0x23) | ((ss & 0x10) >> 2) | ((ss & 0x0C) << 1);
}

// one-hot bf16x8 A-frag word builder: hot halfword c in [0,8), zero otherwise
__device__ __forceinline__ bf16x8 onehot8(int c) {
  union { u32 w[4]; bf16x8 v; } u;
  u32 hv = (c & 1) ? 0x3F800000u : 0x3F80u;
#pragma unroll
  for (int k = 0; k < 4; ++k) u.w[k] = ((c >> 1) == k) ? hv : 0u;
  return u.v;
}

// ---------------------------------------------------------------- prep
// Fused: cvt x (1572864 quads), cvt qkv_w (442368), cvt proj_w (147456),
// rel-pos table x8 (2048 quads). One launch instead of four.
__global__ void prep_kernel(const float* __restrict__ x, const float* __restrict__ qw,
                            const float* __restrict__ pw, const float* __restrict__ rph,
                            const float* __restrict__ rpw, u16* __restrict__ xb,
                            u16* __restrict__ qwb, u16* __restrict__ pwb,
                            u16* __restrict__ tbl) {
  int i = blockIdx.x * 256 + threadIdx.x;   // 2,164,736 total quads
  const float* src;
  u16* dst;
  int j;
  if (i < 1572864) { src = x; dst = xb; j = i; }
  else if (i < 2015232) { src = qw; dst = qwb; j = i - 1572864; }
  else if (i < 2162688) { src = pw; dst = pwb; j = i - 2015232; }
  else {
    int b = (i - 2162688) * 4;
    ushort4 o;
#pragma unroll
    for (int k = 0; k < 4; ++k) {
      int idx = b + k, row = idx >> 6, d = idx & 63;
      float v = 0.f;
      if (row < 63) v = rph[row * 64 + d];
      else if (row >= 64 && row < 127) v = rpw[(row - 64) * 64 + d];
      ((u16*)&o)[k] = f2bf(v * 8.0f);
    }
    *(ushort4*)&tbl[b] = o;
    return;
  }
  float4 v = *(const float4*)(src + j * 4);
  ushort4 o;
  o.x = f2bf(v.x); o.y = f2bf(v.y); o.z = f2bf(v.z); o.w = f2bf(v.w);
  *(ushort4*)(dst + j * 4) = o;
}

// ---------------------------------------------------------------- P gemm
// strips = (q*scale2)[g] . tbl8[j]; scattered into the aug half of Q:
//   Q2[g][64+kw] = rel_w(g,kw), Q2[g][96+kh] = rel_h(g,kh)  (log2 domain)
// 2 row-tiles (256 rows) per block: tbl staged once, both A halves upfront.
__global__ __launch_bounds__(256, 2) void pgemm_kernel(
    const u16* __restrict__ A, const u16* __restrict__ tbl, u16* __restrict__ Q2) {
  __shared__ u16 As[2][128 * 64];
  __shared__ u16 Bs[128 * 64];
  const int tid = threadIdx.x;
  const int lane = tid & 63, wave = tid >> 6;
  const int lr = lane & 15, lg = lane >> 4;
  const int m0 = blockIdx.x * 256;
  const int wm = (wave >> 1) * 64, wn = (wave & 1) * 64;

#pragma unroll
  for (int i = 0; i < 4; ++i) {
    int c = tid + i * 256;
    int row = c >> 3, pp = c & 7;
    int pl = pp ^ (row & 7);  // pre-swizzled source, linear LDS dest
    GLD16(tbl + row * 64 + pl * 8, &Bs[c * 8]);
#pragma unroll
    for (int tt = 0; tt < 2; ++tt)
      GLD16(A + (size_t)(m0 + tt * 128 + row) * 128 + pl * 8, &As[tt][c * 8]);
  }
  __syncthreads();

  bf16x8 b[4][2];
#pragma unroll
  for (int n = 0; n < 4; ++n) {
    int row = wn + n * 16 + lr;
#pragma unroll
    for (int kf = 0; kf < 2; ++kf)
      b[n][kf] = *(const bf16x8*)&Bs[(row * 64 + kf * 32 + lg * 8) ^ ((row & 7) << 3)];
  }

#pragma unroll
  for (int tt = 0; tt < 2; ++tt) {
    bf16x8 a[4][2];
#pragma unroll
    for (int m = 0; m < 4; ++m) {
      int row = wm + m * 16 + lr;
#pragma unroll
      for (int kf = 0; kf < 2; ++kf)
        a[m][kf] = *(const bf16x8*)&As[tt][(row * 64 + kf * 32 + lg * 8) ^ ((row & 7) << 3)];
    }
    f32x4 acc[4][4] = {};
#pragma unroll
    for (int kf = 0; kf < 2; ++kf)
#pragma unroll
      for (int m = 0; m < 4; ++m)
#pragma unroll
        for (int n = 0; n < 4; ++n)
          acc[m][n] = __builtin_amdgcn_mfma_f32_16x16x32_bf16(a[m][kf], b[n][kf], acc[m][n], 0, 0, 0);

#pragma unroll
    for (int m = 0; m < 4; ++m)
#pragma unroll
      for (int n = 0; n < 4; ++n) {
        const int col = wn + n * 16 + lr;
#pragma unroll
        for (int r = 0; r < 4; ++r) {
          const int g = m0 + tt * 128 + wm + m * 16 + lg * 4 + r;
          const int s = g & 1023;
          const int hq = s >> 5, w = s & 31;
          u16 hv = f2bf(acc[m][n][r]);
          if (col < 64) {
            int kh = hq + 31 - col;
            if ((unsigned)kh < 32u) Q2[(size_t)g * 128 + 96 + kh] = hv;
          } else {
            int kw = w + 95 - col;
            if ((unsigned)kw < 32u) Q2[(size_t)g * 128 + 64 + kw] = hv;
          }
        }
      }
  }
}

// ---------------------------------------------------------------- GEMM
// 128x128 tile, BK=64, 512 threads / 8 waves (wave tile 64x32), XOR-swizzled
// LDS, XCD block swizzle, counted vmcnt, loop-carried staging pointers,
// pre-computed fragment LDS offsets (loop-invariant).
// MODE 0: q stride-128 (aug, pre-scaled 0.125*log2e); k stride-64; v^T kappa.
template <int MODE>
__global__ __launch_bounds__(512, 2) void gemm128(
    const u16* __restrict__ A, const u16* __restrict__ B,
    const float* __restrict__ bias, u16* __restrict__ oq, u16* __restrict__ ok,
    u16* __restrict__ ovt, float* __restrict__ ofp) {
  __shared__ u16 As[2][128 * 64];
  __shared__ u16 Bs[2][128 * 64];
  const int tid = threadIdx.x;
  const int lane = tid & 63, wave = tid >> 6;
  const int lr = lane & 15, lg = lane >> 4;

  const int nbx = (MODE == 0) ? 18 : 6;
  const int nwg = nbx * 64;
  int id = blockIdx.y * nbx + blockIdx.x;
  int nid = (id & 7) * (nwg >> 3) + (id >> 3);
  const int m0 = (nid / nbx) * 128, n0 = (nid % nbx) * 128;
  const int wm = (wave >> 2) * 64, wn = (wave & 3) * 32;

  f32x4 acc[4][2] = {};

  // pre-computed fragment LDS offsets (u16 elements)
  int aoff[4][2], boff[2][2];
#pragma unroll
  for (int m = 0; m < 4; ++m) {
    int row = wm + m * 16 + lr;
#pragma unroll
    for (int kf = 0; kf < 2; ++kf)
      aoff[m][kf] = (row * 64 + kf * 32 + lg * 8) ^ ((row & 7) << 3);
  }
#pragma unroll
  for (int n = 0; n < 2; ++n) {
    int row = wn + n * 16 + lr;
#pragma unroll
    for (int kf = 0; kf < 2; ++kf)
      boff[n][kf] = (row * 64 + kf * 32 + lg * 8) ^ ((row & 7) << 3);
  }

  const u16* ap[2];
  const u16* bp[2];
#pragma unroll
  for (int i = 0; i < 2; ++i) {
    int c = tid + i * 512;          // 1024 chunks = 128 rows x 8
    int row = c >> 3, pp = c & 7;
    int pl = pp ^ (row & 7);        // pre-swizzled global source, linear LDS dest
    if constexpr (MODE == 0) {
      ap[i] = A + (size_t)(m0 + row) * 768 + pl * 8;
    } else {
      int g = m0 + row;
      ap[i] = A + ((size_t)((g >> 10) * 12) << 16) + (g & 1023) * 64 + pl * 8;
    }
    bp[i] = B + (size_t)(n0 + row) * 768 + pl * 8;
  }
  constexpr int dA = (MODE == 0) ? 64 : 65536;

  auto stage = [&](int bi) {
#pragma unroll
    for (int i = 0; i < 2; ++i) {
      int c = tid + i * 512;
      GLD16(ap[i], &As[bi][c * 8]);
      GLD16(bp[i], &Bs[bi][c * 8]);
      ap[i] += dA;
      bp[i] += 64;
    }
  };

  stage(0);
#pragma unroll 1
  for (int t = 0; t < 12; ++t) {
    const int cur = t & 1;
    if (t < 11) {
      stage(cur ^ 1);
      asm volatile("s_waitcnt vmcnt(4)" ::: "memory");
    } else {
      asm volatile("s_waitcnt vmcnt(0)" ::: "memory");
    }
    __builtin_amdgcn_sched_barrier(0);
    __builtin_amdgcn_s_barrier();        // entry: buf[cur] ready for all waves
    __builtin_amdgcn_sched_barrier(0);

    bf16x8 a[4][2], b[2][2];
#pragma unroll
    for (int m = 0; m < 4; ++m)
#pragma unroll
      for (int kf = 0; kf < 2; ++kf)
        a[m][kf] = *(const bf16x8*)&As[cur][aoff[m][kf]];
#pragma unroll
    for (int n = 0; n < 2; ++n)
#pragma unroll
      for (int kf = 0; kf < 2; ++kf)
        b[n][kf] = *(const bf16x8*)&Bs[cur][boff[n][kf]];
    __builtin_amdgcn_s_setprio(1);
#pragma unroll
    for (int kf = 0; kf < 2; ++kf)
#pragma unroll
      for (int m = 0; m < 4; ++m)
#pragma unroll
        for (int n = 0; n < 2; ++n)
          acc[m][n] = __builtin_amdgcn_mfma_f32_16x16x32_bf16(a[m][kf], b[n][kf], acc[m][n], 0, 0, 0);
    __builtin_amdgcn_s_setprio(0);

    __builtin_amdgcn_sched_barrier(0);
    __builtin_amdgcn_s_barrier();        // exit: all reads done before overwrite
    __builtin_amdgcn_sched_barrier(0);
  }

#pragma unroll
  for (int m = 0; m < 4; ++m) {
    const int grow0 = m0 + wm + m * 16 + lg * 4;
#pragma unroll
    for (int n = 0; n < 2; ++n) {
      const int gcol = n0 + wn + n * 16 + lr;
      const float bv = bias[gcol];
      if constexpr (MODE == 0) {
        int which = (gcol >= 1536) ? 2 : (gcol >= 768 ? 1 : 0);
        int rem = gcol - which * 768;
        int bh = (grow0 >> 10) * 12 + (rem >> 6);
        if (which == 2) {
          int s0 = grow0 & 1023;
          int colb = (s0 & ~63) | kappa(s0 & 63);  // kappa keeps low 2 bits
          ushort4 pk;
          pk.x = f2bf(acc[m][n][0] + bv);
          pk.y = f2bf(acc[m][n][1] + bv);
          pk.z = f2bf(acc[m][n][2] + bv);
          pk.w = f2bf(acc[m][n][3] + bv);
          *(ushort4*)&ovt[((size_t)bh << 16) + (size_t)(rem & 63) * 1024 + colb] = pk;
        } else if (which == 0) {
          // q: aug layout stride 128, pre-scaled into log2 domain
#pragma unroll
          for (int r = 0; r < 4; ++r) {
            int s = (grow0 & 1023) + r;
            oq[((size_t)bh << 17) + s * 128 + (rem & 63)] =
                f2bf((acc[m][n][r] + bv) * 0.18033688f);
          }
        } else {
          // k: plain stride-64 layout
#pragma unroll
          for (int r = 0; r < 4; ++r) {
            int s = (grow0 & 1023) + r;
            ok[((size_t)bh << 16) + s * 64 + (rem & 63)] = f2bf(acc[m][n][r] + bv);
          }
        }
      } else {
#pragma unroll
        for (int r = 0; r < 4; ++r)
          ofp[(size_t)(grow0 + r) * 768 + gcol] = acc[m][n][r] + bv;
      }
    }
  }
}

// ---------------------------------------------------------------- flash attention
// grid (96 heads, 8 q-tiles); block 256 = 4 waves x 32 q-rows.
// Augmented QK^T with register-synthesized one-hot K-frags. The kw one-hot
// contribution is t-INVARIANT: computed once pre-loop (4 MFMAs) into sacW
// and used as the per-tile accumulator INIT -- saves 8 MFMA/tile. kh one-hot
// stays in-loop (t-dependent). sac IS the final logit (log2 domain).
__global__ __launch_bounds__(256, 2) void attn_kernel(
    const u16* __restrict__ qb, const u16* __restrict__ kb,
    const u16* __restrict__ vtb, u16* __restrict__ ao) {
  __shared__ u16 Ks[2][4096];
  __shared__ u16 Vs[2][4096];

  const int tid = threadIdx.x;
  const int lane = tid & 63, wave = tid >> 6;
  const int lr = lane & 15, lg = lane >> 4;
  const int bh = blockIdx.x;   // head fastest -> all q-tiles of a head on one XCD
  const int q0 = blockIdx.y * 128 + wave * 32;
  const size_t hb2 = (size_t)bh << 17;   // q stride-128 region
  const size_t hbv = (size_t)bh << 16;   // k / v^T / output stride-64 region

  bf16x8 qf[2][4];
#pragma unroll
  for (int m = 0; m < 2; ++m)
#pragma unroll
    for (int kf = 0; kf < 4; ++kf)
      qf[m][kf] = *(const bf16x8*)(qb + hb2 + (size_t)(q0 + m * 16 + lr) * 128 + kf * 32 + lg * 8);

  // kw one-hot contribution (t-independent) -> per-tile accumulator init
  f32x4 sacW[2][2] = {};
#pragma unroll
  for (int h = 0; h < 2; ++h) {
    bf16x8 kwf = onehot8(h * 16 + lr - lg * 8);
#pragma unroll
    for (int m = 0; m < 2; ++m)
      sacW[m][h] = __builtin_amdgcn_mfma_f32_16x16x32_bf16(kwf, qf[m][2], sacW[m][h], 0, 0, 0);
  }

  float lsum[2] = {};
  f32x4 acco[2][4] = {};

  // loop-carried staging pointers
  const u16* kp[2];
  const u16* vp[2];
#pragma unroll
  for (int i = 0; i < 2; ++i) {
    int c = tid + i * 256;
    int row = c >> 3, pp = c & 7;
    int pl = pp ^ (row & 7);  // pre-swizzled global source, linear LDS dest
    kp[i] = kb + hbv + (size_t)row * 64 + pl * 8;       // += 4096 per tile
    vp[i] = vtb + hbv + (size_t)row * 1024 + pl * 8;    // += 64 per tile
  }

  auto stage = [&](int bi) {
#pragma unroll
    for (int i = 0; i < 2; ++i) {
      int c = tid + i * 256;
      GLD16(kp[i], &Ks[bi][c * 8]);
      GLD16(vp[i], &Vs[bi][c * 8]);
      kp[i] += 4096;
      vp[i] += 64;
    }
  };

  stage(0);

#pragma unroll 1
  for (int t = 0; t < 16; ++t) {
    const int cur = t & 1;
    if (t < 15) {
      stage(cur ^ 1);
      asm volatile("s_waitcnt vmcnt(4)" ::: "memory");
    } else {
      asm volatile("s_waitcnt vmcnt(0)" ::: "memory");
    }
    __builtin_amdgcn_sched_barrier(0);
    __builtin_amdgcn_s_barrier();        // entry: buf[cur] ready
    __builtin_amdgcn_sched_barrier(0);

    // kh one-hot A-frags for this tile: hot col 2t+h within [0,32)
    bf16x8 khf[2];
#pragma unroll
    for (int h = 0; h < 2; ++h) khf[h] = onehot8(2 * t + h - lg * 8);

    // QK^T: init from kw contribution; d=0..63 from LDS; kh from register
    f32x4 sac[2][4];
#pragma unroll
    for (int m = 0; m < 2; ++m)
#pragma unroll
      for (int f = 0; f < 4; ++f) sac[m][f] = sacW[m][f & 1];
    __builtin_amdgcn_s_setprio(1);
#pragma unroll
    for (int kf = 0; kf < 2; ++kf) {
#pragma unroll
      for (int f = 0; f < 4; ++f) {
        int row = f * 16 + lr;
        bf16x8 kv = *(const bf16x8*)&Ks[cur][(row * 64 + kf * 32 + lg * 8) ^ ((row & 7) << 3)];
#pragma unroll
        for (int m = 0; m < 2; ++m)
          sac[m][f] = __builtin_amdgcn_mfma_f32_16x16x32_bf16(kv, qf[m][kf], sac[m][f], 0, 0, 0);
      }
    }
#pragma unroll
    for (int f = 0; f < 4; ++f)
#pragma unroll
      for (int m = 0; m < 2; ++m)
        sac[m][f] = __builtin_amdgcn_mfma_f32_16x16x32_bf16(khf[f >> 1], qf[m][3], sac[m][f], 0, 0, 0);
    __builtin_amdgcn_s_setprio(0);

    // softmax: exp2 + deferred sum + packed bf16 (kappa order)
    bf16x8 paf[2][2];
#pragma unroll
    for (int m = 0; m < 2; ++m) {
      union { u32 w[4]; bf16x8 v; } wa, wb;
#pragma unroll
      for (int f = 0; f < 4; ++f) {
        float p0 = __builtin_amdgcn_exp2f(sac[m][f][0]);
        float p1 = __builtin_amdgcn_exp2f(sac[m][f][1]);
        float p2 = __builtin_amdgcn_exp2f(sac[m][f][2]);
        float p3 = __builtin_amdgcn_exp2f(sac[m][f][3]);
        lsum[m] += (p0 + p1) + (p2 + p3);
        u32 w0, w1;
        asm("v_cvt_pk_bf16_f32 %0, %1, %2" : "=v"(w0) : "v"(p0), "v"(p1));
        asm("v_cvt_pk_bf16_f32 %0, %1, %2" : "=v"(w1) : "v"(p2), "v"(p3));
        if (f < 2) { wa.w[f * 2] = w0; wa.w[f * 2 + 1] = w1; }
        else       { wb.w[(f - 2) * 2] = w0; wb.w[(f - 2) * 2 + 1] = w1; }
      }
      paf[m][0] = wa.v;
      paf[m][1] = wb.v;
    }

    // PV: O[q][d], acco row=lg*4+r -> q, col=lr -> d
    __builtin_amdgcn_s_setprio(1);
#pragma unroll
    for (int kf = 0; kf < 2; ++kf) {
#pragma unroll
      for (int fd = 0; fd < 4; ++fd) {
        int drow = fd * 16 + lr;
        bf16x8 vv = *(const bf16x8*)&Vs[cur][(drow * 64 + kf * 32 + lg * 8) ^ ((drow & 7) << 3)];
#pragma unroll
        for (int m = 0; m < 2; ++m)
          acco[m][fd] = __builtin_amdgcn_mfma_f32_16x16x32_bf16(paf[m][kf], vv, acco[m][fd], 0, 0, 0);
      }
    }
    __builtin_amdgcn_s_setprio(0);

    __builtin_amdgcn_sched_barrier(0);
    __builtin_amdgcn_s_barrier();        // exit: reads done before overwrite
    __builtin_amdgcn_sched_barrier(0);
  }

#pragma unroll
  for (int m = 0; m < 2; ++m) {
    float s = lsum[m];
    s += __shfl_xor(s, 16);
    s += __shfl_xor(s, 32);
    float inv = 1.0f / s;  // valid on lane with lr = q-local, any lg
#pragma unroll
    for (int r = 0; r < 4; ++r) {
      int src = (lane & 48) + ((lane & 48) >> 2) + r;
      float invr = __shfl(inv, src);
      int gq = q0 + m * 16 + lg * 4 + r;
#pragma unroll
      for (int fd = 0; fd < 4; ++fd)
        ao[hbv + (size_t)gq * 64 + fd * 16 + lr] = f2bf(acco[m][fd][r] * invr);
    }
  }
}

// ---------------------------------------------------------------- launch
extern "C" void kernel_launch(void* const* d_in, const int* in_sizes, int n_in,
                              void* d_out, int out_size, void* d_ws, size_t ws_size,
                              hipStream_t stream) {
  const float* x = (const float*)d_in[0];
  const float* qkv_w = (const float*)d_in[1];
  const float* qkv_b = (const float*)d_in[2];
  const float* proj_w = (const float*)d_in[3];
  const float* proj_b = (const float*)d_in[4];
  const float* rel_pos_h = (const float*)d_in[5];
  const float* rel_pos_w = (const float*)d_in[6];
  float* out = (float*)d_out;

  char* ws = (char*)d_ws;
  u16* x_bf = (u16*)(ws + 0);              // 12,582,912 B (reused as attn out)
  u16* qkvw_bf = (u16*)(ws + 12582912);    //  3,538,944
  u16* projw_bf = (u16*)(ws + 16121856);   //  1,179,648
  u16* qbuf2 = (u16*)(ws + 17301504);      // 25,165,824 (96x1024x128, aug Q)
  u16* kbuf = (u16*)(ws + 42467328);       // 12,582,912 (96x1024x64)
  u16* vtbuf = (u16*)(ws + 55050240);      // 12,582,912
  u16* tbl = (u16*)(ws + 67633152);        //     16,384 -> total 67,649,536
  u16* aobuf = x_bf;                        // alias: x_bf dead after QKV gemm

  prep_kernel<<<8456, 256, 0, stream>>>(x, qkv_w, proj_w, rel_pos_h, rel_pos_w,
                                        x_bf, qkvw_bf, projw_bf, tbl);

  gemm128<0><<<dim3(18, 64), 512, 0, stream>>>(x_bf, qkvw_bf, qkv_b, qbuf2, kbuf, vtbuf, nullptr);

  pgemm_kernel<<<384, 256, 0, stream>>>(qbuf2, tbl, qbuf2);

  attn_kernel<<<dim3(96, 8), 256, 0, stream>>>(qbuf2, kbuf, vtbuf, aobuf);

  gemm128<1><<<dim3(6, 64), 512, 0, stream>>>(aobuf, projw_bf, proj_b, nullptr, nullptr, nullptr, out);
}